// Round 1
// baseline (2357.308 us; speedup 1.0000x reference)
//
#include <hip/hip_runtime.h>

#define DD 128
#define D2 256

// ---------------- scatter: agg[dst] += relu(x[src] + edge_attr) ----------------
__global__ __launch_bounds__(256) void scatter_relu_sum(
    const float* __restrict__ x, const float* __restrict__ ea,
    const int* __restrict__ src, const int* __restrict__ dst,
    float* __restrict__ agg, int E)
{
    int idx = blockIdx.x * 256 + threadIdx.x;
    if (idx >= E * 32) return;
    int e = idx >> 5;
    int c = (idx & 31) << 2;
    int s = src[e], d = dst[e];
    float4 xv = *(const float4*)(x + (size_t)s * DD + c);
    float4 ev = *(const float4*)(ea + (size_t)e * DD + c);
    float* o = agg + (size_t)d * DD + c;
    atomicAdd(o + 0, fmaxf(xv.x + ev.x, 0.f));
    atomicAdd(o + 1, fmaxf(xv.y + ev.y, 0.f));
    atomicAdd(o + 2, fmaxf(xv.z + ev.z, 0.f));
    atomicAdd(o + 3, fmaxf(xv.w + ev.w, 0.f));
}

// ------------- GEMM A: out[N,256] = LNrelu(A[N,128] @ W[128,256] + b) -------------
// block = 256 threads, BM=32 nodes. Thread (cq=tid&63 -> cols cq*4..+3,
// mq=tid>>6 -> nodes mq*8..+7). Wave w == mq group -> full-wave LN reduce.
__global__ __launch_bounds__(256) void gemm_a_ln_relu(
    const float* __restrict__ A, const float* __restrict__ W,
    const float* __restrict__ bias, const float* __restrict__ g,
    const float* __restrict__ be, float* __restrict__ out, int Nn)
{
    __shared__ float a_s[32][DD];
    __shared__ float w_s[32][D2];
    const int tid = threadIdx.x;
    const int row0 = blockIdx.x * 32;
    const int cq = tid & 63, mq = tid >> 6;
    const int c0 = cq * 4;

    #pragma unroll
    for (int i = 0; i < 4; ++i) {            // 32x128 A tile, float4
        int lin = tid + i * 256;             // 0..1023
        int m = lin >> 5, j = (lin & 31) * 4;
        int r = row0 + m; if (r >= Nn) r = Nn - 1;
        *(float4*)&a_s[m][j] = *(const float4*)&A[(size_t)r * DD + j];
    }

    float acc[8][4] = {};
    for (int kc = 0; kc < 4; ++kc) {
        __syncthreads();
        #pragma unroll
        for (int i = 0; i < 8; ++i) {        // 32x256 W chunk, float4
            int lin = tid + i * 256;         // 0..2047
            int kk = lin >> 6, j = (lin & 63) * 4;
            *(float4*)&w_s[kk][j] = *(const float4*)&W[(size_t)(kc * 32 + kk) * D2 + j];
        }
        __syncthreads();
        #pragma unroll
        for (int k = 0; k < 32; ++k) {
            float4 wv = *(float4*)&w_s[k][c0];
            int kg = kc * 32 + k;
            #pragma unroll
            for (int m = 0; m < 8; ++m) {
                float av = a_s[mq * 8 + m][kg];
                acc[m][0] = fmaf(av, wv.x, acc[m][0]);
                acc[m][1] = fmaf(av, wv.y, acc[m][1]);
                acc[m][2] = fmaf(av, wv.z, acc[m][2]);
                acc[m][3] = fmaf(av, wv.w, acc[m][3]);
            }
        }
    }

    float4 bv = *(const float4*)&bias[c0];
    float4 gv = *(const float4*)&g[c0];
    float4 ev = *(const float4*)&be[c0];
    #pragma unroll
    for (int m = 0; m < 8; ++m) {
        float y0 = acc[m][0] + bv.x, y1 = acc[m][1] + bv.y;
        float y2 = acc[m][2] + bv.z, y3 = acc[m][3] + bv.w;
        float s = y0 + y1 + y2 + y3;
        float sq = y0 * y0 + y1 * y1 + y2 * y2 + y3 * y3;
        #pragma unroll
        for (int off = 32; off >= 1; off >>= 1) {
            s += __shfl_xor(s, off, 64);
            sq += __shfl_xor(sq, off, 64);
        }
        float mean = s * (1.f / D2);
        float rstd = rsqrtf(sq * (1.f / D2) - mean * mean + 1e-5f);
        int r = row0 + mq * 8 + m;
        if (r < Nn) {
            float4 o;
            o.x = fmaxf((y0 - mean) * rstd * gv.x + ev.x, 0.f);
            o.y = fmaxf((y1 - mean) * rstd * gv.y + ev.y, 0.f);
            o.z = fmaxf((y2 - mean) * rstd * gv.z + ev.z, 0.f);
            o.w = fmaxf((y3 - mean) * rstd * gv.w + ev.w, 0.f);
            *(float4*)&out[(size_t)r * D2 + c0] = o;
        }
    }
}

// ------ GEMM B: out[N,128] = LN(relu(X[N,256] @ W[256,128] + b)) (relu BEFORE LN) ------
// block = 256 threads, BM=64. cq=tid&31 -> cols cq*4, mq=tid>>5 -> nodes mq*8..+7.
// LN over 128 cols = 32 lanes -> half-wave butterfly (xor <= 16).
__global__ __launch_bounds__(256) void gemm_b_relu_ln(
    const float* __restrict__ X, const float* __restrict__ W,
    const float* __restrict__ bias, const float* __restrict__ g,
    const float* __restrict__ be, float* __restrict__ out, int Nn)
{
    __shared__ float a_s[64][64];
    __shared__ float w_s[64][DD];
    const int tid = threadIdx.x;
    const int row0 = blockIdx.x * 64;
    const int cq = tid & 31, mq = tid >> 5;
    const int c0 = cq * 4;

    float acc[8][4] = {};
    for (int kc = 0; kc < 4; ++kc) {
        __syncthreads();
        #pragma unroll
        for (int i = 0; i < 4; ++i) {        // 64x64 A chunk
            int lin = tid + i * 256;         // 0..1023
            int m = lin >> 4, j = (lin & 15) * 4;
            int r = row0 + m; if (r >= Nn) r = Nn - 1;
            *(float4*)&a_s[m][j] = *(const float4*)&X[(size_t)r * D2 + kc * 64 + j];
        }
        #pragma unroll
        for (int i = 0; i < 8; ++i) {        // 64x128 W chunk
            int lin = tid + i * 256;         // 0..2047
            int kk = lin >> 5, j = (lin & 31) * 4;
            *(float4*)&w_s[kk][j] = *(const float4*)&W[(size_t)(kc * 64 + kk) * DD + j];
        }
        __syncthreads();
        #pragma unroll
        for (int k = 0; k < 64; ++k) {
            float4 wv = *(float4*)&w_s[k][c0];
            #pragma unroll
            for (int m = 0; m < 8; ++m) {
                float av = a_s[mq * 8 + m][k];
                acc[m][0] = fmaf(av, wv.x, acc[m][0]);
                acc[m][1] = fmaf(av, wv.y, acc[m][1]);
                acc[m][2] = fmaf(av, wv.z, acc[m][2]);
                acc[m][3] = fmaf(av, wv.w, acc[m][3]);
            }
        }
    }

    float4 bv = *(const float4*)&bias[c0];
    float4 gv = *(const float4*)&g[c0];
    float4 ev = *(const float4*)&be[c0];
    #pragma unroll
    for (int m = 0; m < 8; ++m) {
        float y0 = fmaxf(acc[m][0] + bv.x, 0.f);
        float y1 = fmaxf(acc[m][1] + bv.y, 0.f);
        float y2 = fmaxf(acc[m][2] + bv.z, 0.f);
        float y3 = fmaxf(acc[m][3] + bv.w, 0.f);
        float s = y0 + y1 + y2 + y3;
        float sq = y0 * y0 + y1 * y1 + y2 * y2 + y3 * y3;
        #pragma unroll
        for (int off = 16; off >= 1; off >>= 1) {
            s += __shfl_xor(s, off, 64);
            sq += __shfl_xor(sq, off, 64);
        }
        float mean = s * (1.f / DD);
        float rstd = rsqrtf(sq * (1.f / DD) - mean * mean + 1e-5f);
        int r = row0 + mq * 8 + m;
        if (r < Nn) {
            float4 o;
            o.x = (y0 - mean) * rstd * gv.x + ev.x;
            o.y = (y1 - mean) * rstd * gv.y + ev.y;
            o.z = (y2 - mean) * rstd * gv.z + ev.z;
            o.w = (y3 - mean) * rstd * gv.w + ev.w;
            *(float4*)&out[(size_t)r * DD + c0] = o;
        }
    }
}

// ------ final: out[N,128] = relu(H1[N,128] @ W[0:128,:] + H2[N,128] @ W[128:256,:] + b) ------
__global__ __launch_bounds__(256) void gemm_final(
    const float* __restrict__ H1, const float* __restrict__ H2,
    const float* __restrict__ W, const float* __restrict__ bias,
    float* __restrict__ out, int Nn)
{
    __shared__ float a_s[64][64];
    __shared__ float w_s[64][DD];
    const int tid = threadIdx.x;
    const int row0 = blockIdx.x * 64;
    const int cq = tid & 31, mq = tid >> 5;
    const int c0 = cq * 4;

    float acc[8][4] = {};
    for (int kc = 0; kc < 4; ++kc) {
        const float* Xsrc = (kc < 2) ? H1 : H2;
        int kof = (kc & 1) * 64;
        __syncthreads();
        #pragma unroll
        for (int i = 0; i < 4; ++i) {
            int lin = tid + i * 256;
            int m = lin >> 4, j = (lin & 15) * 4;
            int r = row0 + m; if (r >= Nn) r = Nn - 1;
            *(float4*)&a_s[m][j] = *(const float4*)&Xsrc[(size_t)r * DD + kof + j];
        }
        #pragma unroll
        for (int i = 0; i < 8; ++i) {
            int lin = tid + i * 256;
            int kk = lin >> 5, j = (lin & 31) * 4;
            *(float4*)&w_s[kk][j] = *(const float4*)&W[(size_t)(kc * 64 + kk) * DD + j];
        }
        __syncthreads();
        #pragma unroll
        for (int k = 0; k < 64; ++k) {
            float4 wv = *(float4*)&w_s[k][c0];
            #pragma unroll
            for (int m = 0; m < 8; ++m) {
                float av = a_s[mq * 8 + m][k];
                acc[m][0] = fmaf(av, wv.x, acc[m][0]);
                acc[m][1] = fmaf(av, wv.y, acc[m][1]);
                acc[m][2] = fmaf(av, wv.z, acc[m][2]);
                acc[m][3] = fmaf(av, wv.w, acc[m][3]);
            }
        }
    }

    float4 bv = *(const float4*)&bias[c0];
    #pragma unroll
    for (int m = 0; m < 8; ++m) {
        int r = row0 + mq * 8 + m;
        if (r < Nn) {
            float4 o;
            o.x = fmaxf(acc[m][0] + bv.x, 0.f);
            o.y = fmaxf(acc[m][1] + bv.y, 0.f);
            o.z = fmaxf(acc[m][2] + bv.z, 0.f);
            o.w = fmaxf(acc[m][3] + bv.w, 0.f);
            *(float4*)&out[(size_t)r * DD + c0] = o;
        }
    }
}

extern "C" void kernel_launch(void* const* d_in, const int* in_sizes, int n_in,
                              void* d_out, int out_size, void* d_ws, size_t ws_size,
                              hipStream_t stream)
{
    const float* x    = (const float*)d_in[0];
    const int*   ei   = (const int*)d_in[1];
    const float* ea   = (const float*)d_in[2];
    // d_in[3] = pos (unused)
    const float* w1a  = (const float*)d_in[4];
    const float* b1a  = (const float*)d_in[5];
    const float* g1a  = (const float*)d_in[6];
    const float* be1a = (const float*)d_in[7];
    const float* w1b  = (const float*)d_in[8];
    const float* b1b  = (const float*)d_in[9];
    const float* w2a  = (const float*)d_in[10];
    const float* b2a  = (const float*)d_in[11];
    const float* g2a  = (const float*)d_in[12];
    const float* be2a = (const float*)d_in[13];
    const float* w2b  = (const float*)d_in[14];
    const float* b2b  = (const float*)d_in[15];
    const float* ng1  = (const float*)d_in[16];
    const float* nb1  = (const float*)d_in[17];
    const float* ng2  = (const float*)d_in[18];
    const float* nb2  = (const float*)d_in[19];
    const float* wl   = (const float*)d_in[20];
    const float* bl   = (const float*)d_in[21];

    const int N = in_sizes[0] / DD;
    const int E = in_sizes[1] / 2;
    const int* src = ei;
    const int* dst = ei + E;

    float* agg = (float*)d_ws;                  // N*128 f32
    float* mid = agg + (size_t)N * DD;          // N*256 f32
    float* h1  = mid + (size_t)N * D2;          // N*128 f32
    float* h2  = agg;                           // reuse agg after conv2-A consumes it
    float* out = (float*)d_out;

    const int gb32 = (N + 31) / 32;
    const int gb64 = (N + 63) / 64;
    const int gsc  = (E * 32 + 255) / 256;

    // ---- conv1 ----
    hipMemcpyAsync(agg, x, (size_t)N * DD * sizeof(float), hipMemcpyDeviceToDevice, stream);
    scatter_relu_sum<<<gsc, 256, 0, stream>>>(x, ea, src, dst, agg, E);
    gemm_a_ln_relu<<<gb32, 256, 0, stream>>>(agg, w1a, b1a, g1a, be1a, mid, N);
    gemm_b_relu_ln<<<gb64, 256, 0, stream>>>(mid, w1b, b1b, ng1, nb1, h1, N);

    // ---- conv2 ----
    hipMemcpyAsync(agg, h1, (size_t)N * DD * sizeof(float), hipMemcpyDeviceToDevice, stream);
    scatter_relu_sum<<<gsc, 256, 0, stream>>>(h1, ea, src, dst, agg, E);
    gemm_a_ln_relu<<<gb32, 256, 0, stream>>>(agg, w2a, b2a, g2a, be2a, mid, N);
    gemm_b_relu_ln<<<gb64, 256, 0, stream>>>(mid, w2b, b2b, ng2, nb2, h2, N);

    // ---- final linear ----
    gemm_final<<<gb64, 256, 0, stream>>>(h1, h2, wl, bl, out, N);
}

// Round 2
// 584.853 us; speedup vs baseline: 4.0306x; 4.0306x over previous
//
#include <hip/hip_runtime.h>

#define DD 128
#define D2 256

// ---------------- CSR build ----------------
__global__ __launch_bounds__(256) void hist_kernel(
    const int* __restrict__ dst, int* __restrict__ deg, int E)
{
    int e = blockIdx.x * 256 + threadIdx.x;
    if (e < E) atomicAdd(&deg[dst[e]], 1);
}

// single-block exclusive scan over deg[0..Nn) -> offs[0..Nn]
__global__ __launch_bounds__(1024) void exscan_kernel(
    const int* __restrict__ deg, int* __restrict__ offs, int Nn)
{
    __shared__ int wsum[16];
    __shared__ int carry;
    const int t = threadIdx.x, lane = t & 63, w = t >> 6;
    if (t == 0) carry = 0;
    __syncthreads();
    for (int base = 0; base < Nn; base += 4096) {
        int i0 = base + t * 4;
        int a = 0, b = 0, c = 0, d = 0;
        if (i0 + 3 < Nn) {
            int4 v = *(const int4*)(deg + i0);
            a = v.x; b = v.y; c = v.z; d = v.w;
        } else {
            if (i0     < Nn) a = deg[i0];
            if (i0 + 1 < Nn) b = deg[i0 + 1];
            if (i0 + 2 < Nn) c = deg[i0 + 2];
            if (i0 + 3 < Nn) d = deg[i0 + 3];
        }
        int tot = a + b + c + d;
        int inc = tot;
        #pragma unroll
        for (int o = 1; o < 64; o <<= 1) {
            int n = __shfl_up(inc, o, 64);
            if (lane >= o) inc += n;
        }
        if (lane == 63) wsum[w] = inc;
        __syncthreads();
        if (w == 0) {
            int ws = (lane < 16) ? wsum[lane] : 0;
            #pragma unroll
            for (int o = 1; o < 16; o <<= 1) {
                int n = __shfl_up(ws, o, 64);
                if (lane >= o) ws += n;
            }
            if (lane < 16) wsum[lane] = ws;
        }
        __syncthreads();
        int wbase = (w > 0) ? wsum[w - 1] : 0;
        int excl = carry + wbase + (inc - tot);
        if (i0     < Nn) offs[i0]     = excl;
        if (i0 + 1 < Nn) offs[i0 + 1] = excl + a;
        if (i0 + 2 < Nn) offs[i0 + 2] = excl + a + b;
        if (i0 + 3 < Nn) offs[i0 + 3] = excl + a + b + c;
        int iter_total = wsum[15];
        __syncthreads();
        if (t == 0) carry += iter_total;
        __syncthreads();
    }
    if (t == 0) offs[Nn] = carry;
}

__global__ __launch_bounds__(256) void fill_kernel(
    const int* __restrict__ dst, const int* __restrict__ offs,
    int* __restrict__ cursor, int* __restrict__ eids, int E)
{
    int e = blockIdx.x * 256 + threadIdx.x;
    if (e < E) {
        int d = dst[e];
        int p = atomicAdd(&cursor[d], 1);
        eids[offs[d] + p] = e;
    }
}

// --------- aggregate: agg[n] = x[n] + sum_{e: dst=n} relu(x[src[e]] + ea[e]) ---------
// one wave per node; edge ids/srcs prefetched into lanes, broadcast via shfl
__global__ __launch_bounds__(256) void aggregate_csr(
    const float* __restrict__ x, const float* __restrict__ ea,
    const int* __restrict__ src, const int* __restrict__ offs,
    const int* __restrict__ eids, float* __restrict__ agg, int Nn)
{
    int node = blockIdx.x * 4 + (threadIdx.x >> 6);
    if (node >= Nn) return;
    int lane = threadIdx.x & 63;
    int beg = offs[node], end = offs[node + 1];
    float2 acc = *(const float2*)(x + (size_t)node * DD + lane * 2);
    for (int cb = beg; cb < end; cb += 64) {
        int cnt = min(64, end - cb);
        int myeid = 0, mysrc = 0;
        if (lane < cnt) { myeid = eids[cb + lane]; mysrc = src[myeid]; }
        for (int i = 0; i < cnt; ++i) {
            int e = __shfl(myeid, i, 64);
            int s = __shfl(mysrc, i, 64);
            float2 ev = *(const float2*)(ea + (size_t)e * DD + lane * 2);
            float2 xv = *(const float2*)(x + (size_t)s * DD + lane * 2);
            acc.x += fmaxf(xv.x + ev.x, 0.f);
            acc.y += fmaxf(xv.y + ev.y, 0.f);
        }
    }
    *(float2*)(agg + (size_t)node * DD + lane * 2) = acc;
}

// ------------- GEMM A: out[N,256] = LNrelu(A[N,128] @ W[128,256] + b) -------------
__global__ __launch_bounds__(256) void gemm_a_ln_relu(
    const float* __restrict__ A, const float* __restrict__ W,
    const float* __restrict__ bias, const float* __restrict__ g,
    const float* __restrict__ be, float* __restrict__ out, int Nn)
{
    __shared__ float a_s[32][DD];
    __shared__ float w_s[32][D2];
    const int tid = threadIdx.x;
    const int row0 = blockIdx.x * 32;
    const int cq = tid & 63, mq = tid >> 6;
    const int c0 = cq * 4;

    #pragma unroll
    for (int i = 0; i < 4; ++i) {
        int lin = tid + i * 256;
        int m = lin >> 5, j = (lin & 31) * 4;
        int r = row0 + m; if (r >= Nn) r = Nn - 1;
        *(float4*)&a_s[m][j] = *(const float4*)&A[(size_t)r * DD + j];
    }

    float acc[8][4] = {};
    for (int kc = 0; kc < 4; ++kc) {
        __syncthreads();
        #pragma unroll
        for (int i = 0; i < 8; ++i) {
            int lin = tid + i * 256;
            int kk = lin >> 6, j = (lin & 63) * 4;
            *(float4*)&w_s[kk][j] = *(const float4*)&W[(size_t)(kc * 32 + kk) * D2 + j];
        }
        __syncthreads();
        #pragma unroll
        for (int k = 0; k < 32; ++k) {
            float4 wv = *(float4*)&w_s[k][c0];
            int kg = kc * 32 + k;
            #pragma unroll
            for (int m = 0; m < 8; ++m) {
                float av = a_s[mq * 8 + m][kg];
                acc[m][0] = fmaf(av, wv.x, acc[m][0]);
                acc[m][1] = fmaf(av, wv.y, acc[m][1]);
                acc[m][2] = fmaf(av, wv.z, acc[m][2]);
                acc[m][3] = fmaf(av, wv.w, acc[m][3]);
            }
        }
    }

    float4 bv = *(const float4*)&bias[c0];
    float4 gv = *(const float4*)&g[c0];
    float4 ev = *(const float4*)&be[c0];
    #pragma unroll
    for (int m = 0; m < 8; ++m) {
        float y0 = acc[m][0] + bv.x, y1 = acc[m][1] + bv.y;
        float y2 = acc[m][2] + bv.z, y3 = acc[m][3] + bv.w;
        float s = y0 + y1 + y2 + y3;
        float sq = y0 * y0 + y1 * y1 + y2 * y2 + y3 * y3;
        #pragma unroll
        for (int off = 32; off >= 1; off >>= 1) {
            s += __shfl_xor(s, off, 64);
            sq += __shfl_xor(sq, off, 64);
        }
        float mean = s * (1.f / D2);
        float rstd = rsqrtf(sq * (1.f / D2) - mean * mean + 1e-5f);
        int r = row0 + mq * 8 + m;
        if (r < Nn) {
            float4 o;
            o.x = fmaxf((y0 - mean) * rstd * gv.x + ev.x, 0.f);
            o.y = fmaxf((y1 - mean) * rstd * gv.y + ev.y, 0.f);
            o.z = fmaxf((y2 - mean) * rstd * gv.z + ev.z, 0.f);
            o.w = fmaxf((y3 - mean) * rstd * gv.w + ev.w, 0.f);
            *(float4*)&out[(size_t)r * D2 + c0] = o;
        }
    }
}

// ------ GEMM B: out[N,128] = LN(relu(X[N,256] @ W[256,128] + b)) ------
__global__ __launch_bounds__(256) void gemm_b_relu_ln(
    const float* __restrict__ X, const float* __restrict__ W,
    const float* __restrict__ bias, const float* __restrict__ g,
    const float* __restrict__ be, float* __restrict__ out, int Nn)
{
    __shared__ float a_s[64][64];
    __shared__ float w_s[64][DD];
    const int tid = threadIdx.x;
    const int row0 = blockIdx.x * 64;
    const int cq = tid & 31, mq = tid >> 5;
    const int c0 = cq * 4;

    float acc[8][4] = {};
    for (int kc = 0; kc < 4; ++kc) {
        __syncthreads();
        #pragma unroll
        for (int i = 0; i < 4; ++i) {
            int lin = tid + i * 256;
            int m = lin >> 4, j = (lin & 15) * 4;
            int r = row0 + m; if (r >= Nn) r = Nn - 1;
            *(float4*)&a_s[m][j] = *(const float4*)&X[(size_t)r * D2 + kc * 64 + j];
        }
        #pragma unroll
        for (int i = 0; i < 8; ++i) {
            int lin = tid + i * 256;
            int kk = lin >> 5, j = (lin & 31) * 4;
            *(float4*)&w_s[kk][j] = *(const float4*)&W[(size_t)(kc * 64 + kk) * DD + j];
        }
        __syncthreads();
        #pragma unroll
        for (int k = 0; k < 64; ++k) {
            float4 wv = *(float4*)&w_s[k][c0];
            #pragma unroll
            for (int m = 0; m < 8; ++m) {
                float av = a_s[mq * 8 + m][k];
                acc[m][0] = fmaf(av, wv.x, acc[m][0]);
                acc[m][1] = fmaf(av, wv.y, acc[m][1]);
                acc[m][2] = fmaf(av, wv.z, acc[m][2]);
                acc[m][3] = fmaf(av, wv.w, acc[m][3]);
            }
        }
    }

    float4 bv = *(const float4*)&bias[c0];
    float4 gv = *(const float4*)&g[c0];
    float4 ev = *(const float4*)&be[c0];
    #pragma unroll
    for (int m = 0; m < 8; ++m) {
        float y0 = fmaxf(acc[m][0] + bv.x, 0.f);
        float y1 = fmaxf(acc[m][1] + bv.y, 0.f);
        float y2 = fmaxf(acc[m][2] + bv.z, 0.f);
        float y3 = fmaxf(acc[m][3] + bv.w, 0.f);
        float s = y0 + y1 + y2 + y3;
        float sq = y0 * y0 + y1 * y1 + y2 * y2 + y3 * y3;
        #pragma unroll
        for (int off = 16; off >= 1; off >>= 1) {
            s += __shfl_xor(s, off, 64);
            sq += __shfl_xor(sq, off, 64);
        }
        float mean = s * (1.f / DD);
        float rstd = rsqrtf(sq * (1.f / DD) - mean * mean + 1e-5f);
        int r = row0 + mq * 8 + m;
        if (r < Nn) {
            float4 o;
            o.x = (y0 - mean) * rstd * gv.x + ev.x;
            o.y = (y1 - mean) * rstd * gv.y + ev.y;
            o.z = (y2 - mean) * rstd * gv.z + ev.z;
            o.w = (y3 - mean) * rstd * gv.w + ev.w;
            *(float4*)&out[(size_t)r * DD + c0] = o;
        }
    }
}

// ------ final: out[N,128] = relu([H1|H2] @ W + b) ------
__global__ __launch_bounds__(256) void gemm_final(
    const float* __restrict__ H1, const float* __restrict__ H2,
    const float* __restrict__ W, const float* __restrict__ bias,
    float* __restrict__ out, int Nn)
{
    __shared__ float a_s[64][64];
    __shared__ float w_s[64][DD];
    const int tid = threadIdx.x;
    const int row0 = blockIdx.x * 64;
    const int cq = tid & 31, mq = tid >> 5;
    const int c0 = cq * 4;

    float acc[8][4] = {};
    for (int kc = 0; kc < 4; ++kc) {
        const float* Xsrc = (kc < 2) ? H1 : H2;
        int kof = (kc & 1) * 64;
        __syncthreads();
        #pragma unroll
        for (int i = 0; i < 4; ++i) {
            int lin = tid + i * 256;
            int m = lin >> 4, j = (lin & 15) * 4;
            int r = row0 + m; if (r >= Nn) r = Nn - 1;
            *(float4*)&a_s[m][j] = *(const float4*)&Xsrc[(size_t)r * DD + kof + j];
        }
        #pragma unroll
        for (int i = 0; i < 8; ++i) {
            int lin = tid + i * 256;
            int kk = lin >> 5, j = (lin & 31) * 4;
            *(float4*)&w_s[kk][j] = *(const float4*)&W[(size_t)(kc * 64 + kk) * DD + j];
        }
        __syncthreads();
        #pragma unroll
        for (int k = 0; k < 64; ++k) {
            float4 wv = *(float4*)&w_s[k][c0];
            #pragma unroll
            for (int m = 0; m < 8; ++m) {
                float av = a_s[mq * 8 + m][k];
                acc[m][0] = fmaf(av, wv.x, acc[m][0]);
                acc[m][1] = fmaf(av, wv.y, acc[m][1]);
                acc[m][2] = fmaf(av, wv.z, acc[m][2]);
                acc[m][3] = fmaf(av, wv.w, acc[m][3]);
            }
        }
    }

    float4 bv = *(const float4*)&bias[c0];
    #pragma unroll
    for (int m = 0; m < 8; ++m) {
        int r = row0 + mq * 8 + m;
        if (r < Nn) {
            float4 o;
            o.x = fmaxf(acc[m][0] + bv.x, 0.f);
            o.y = fmaxf(acc[m][1] + bv.y, 0.f);
            o.z = fmaxf(acc[m][2] + bv.z, 0.f);
            o.w = fmaxf(acc[m][3] + bv.w, 0.f);
            *(float4*)&out[(size_t)r * DD + c0] = o;
        }
    }
}

extern "C" void kernel_launch(void* const* d_in, const int* in_sizes, int n_in,
                              void* d_out, int out_size, void* d_ws, size_t ws_size,
                              hipStream_t stream)
{
    const float* x    = (const float*)d_in[0];
    const int*   ei   = (const int*)d_in[1];
    const float* ea   = (const float*)d_in[2];
    const float* w1a  = (const float*)d_in[4];
    const float* b1a  = (const float*)d_in[5];
    const float* g1a  = (const float*)d_in[6];
    const float* be1a = (const float*)d_in[7];
    const float* w1b  = (const float*)d_in[8];
    const float* b1b  = (const float*)d_in[9];
    const float* w2a  = (const float*)d_in[10];
    const float* b2a  = (const float*)d_in[11];
    const float* g2a  = (const float*)d_in[12];
    const float* be2a = (const float*)d_in[13];
    const float* w2b  = (const float*)d_in[14];
    const float* b2b  = (const float*)d_in[15];
    const float* ng1  = (const float*)d_in[16];
    const float* nb1  = (const float*)d_in[17];
    const float* ng2  = (const float*)d_in[18];
    const float* nb2  = (const float*)d_in[19];
    const float* wl   = (const float*)d_in[20];
    const float* bl   = (const float*)d_in[21];

    const int N = in_sizes[0] / DD;
    const int E = in_sizes[1] / 2;
    const int* src = ei;
    const int* dst = ei + E;

    float* agg = (float*)d_ws;                    // N*128 f32
    float* mid = agg + (size_t)N * DD;            // N*256 f32
    float* h1  = mid + (size_t)N * D2;            // N*128 f32
    float* h2  = agg;                             // reuse after conv2-A consumes agg
    int*   deg    = (int*)(h1 + (size_t)N * DD);  // N
    int*   offs   = deg + N;                      // N+1
    int*   cursor = offs + N + 1;                 // N
    int*   eids   = cursor + N;                   // E
    float* out = (float*)d_out;

    const int gb32 = (N + 31) / 32;
    const int gb64 = (N + 63) / 64;
    const int gE   = (E + 255) / 256;
    const int gagg = (N + 3) / 4;

    // ---- CSR build (shared by both convs) ----
    hipMemsetAsync(deg, 0, (size_t)N * sizeof(int), stream);
    hipMemsetAsync(cursor, 0, (size_t)N * sizeof(int), stream);
    hist_kernel<<<gE, 256, 0, stream>>>(dst, deg, E);
    exscan_kernel<<<1, 1024, 0, stream>>>(deg, offs, N);
    fill_kernel<<<gE, 256, 0, stream>>>(dst, offs, cursor, eids, E);

    // ---- conv1 ----
    aggregate_csr<<<gagg, 256, 0, stream>>>(x, ea, src, offs, eids, agg, N);
    gemm_a_ln_relu<<<gb32, 256, 0, stream>>>(agg, w1a, b1a, g1a, be1a, mid, N);
    gemm_b_relu_ln<<<gb64, 256, 0, stream>>>(mid, w1b, b1b, ng1, nb1, h1, N);

    // ---- conv2 ----
    aggregate_csr<<<gagg, 256, 0, stream>>>(h1, ea, src, offs, eids, agg, N);
    gemm_a_ln_relu<<<gb32, 256, 0, stream>>>(agg, w2a, b2a, g2a, be2a, mid, N);
    gemm_b_relu_ln<<<gb64, 256, 0, stream>>>(mid, w2b, b2b, ng2, nb2, h2, N);

    // ---- final linear ----
    gemm_final<<<gb64, 256, 0, stream>>>(h1, h2, wl, bl, out, N);
}

// Round 3
// 425.110 us; speedup vs baseline: 5.5452x; 1.3758x over previous
//
#include <hip/hip_runtime.h>

#define DD 128
#define D2 256

typedef __attribute__((ext_vector_type(8))) short bf16x8;
typedef __attribute__((ext_vector_type(4))) float f32x4;
typedef __attribute__((ext_vector_type(4))) unsigned short us4;

#define MFMA16(a,b,c) __builtin_amdgcn_mfma_f32_16x16x32_bf16(a,b,c,0,0,0)

__device__ __forceinline__ unsigned short f2bf(float f) {
    unsigned int u = __float_as_uint(f);
    u += 0x7FFF + ((u >> 16) & 1);
    return (unsigned short)(u >> 16);
}

// ---------------- weight pre-pack: fp32 [K][Nc] -> bf16 frag-linear ----------------
// frag f (cf=f/nks, ks=f%nks), lane l, j: W[ks*32+(l>>4)*8+j][cf*16+(l&15)]
__global__ __launch_bounds__(64) void pack_weights(
    const float* __restrict__ w1a, const float* __restrict__ w1b,
    const float* __restrict__ w2a, const float* __restrict__ w2b,
    const float* __restrict__ wl,
    unsigned short* __restrict__ o1a, unsigned short* __restrict__ o1b,
    unsigned short* __restrict__ o2a, unsigned short* __restrict__ o2b,
    unsigned short* __restrict__ ol)
{
    int widx = blockIdx.x >> 6;
    int f = blockIdx.x & 63;
    int lane = threadIdx.x;
    const float* W; unsigned short* O; int nks, Nc;
    switch (widx) {
        case 0: W = w1a; O = o1a; nks = 4; Nc = 256; break;
        case 1: W = w1b; O = o1b; nks = 8; Nc = 128; break;
        case 2: W = w2a; O = o2a; nks = 4; Nc = 256; break;
        case 3: W = w2b; O = o2b; nks = 8; Nc = 128; break;
        default: W = wl; O = ol;  nks = 8; Nc = 128; break;
    }
    int cf = f / nks, ks = f % nks;
    int col = cf * 16 + (lane & 15);
    int k0 = ks * 32 + (lane >> 4) * 8;
    unsigned short t[8];
    #pragma unroll
    for (int j = 0; j < 8; ++j) t[j] = f2bf(W[(size_t)(k0 + j) * Nc + col]);
    us4* dst = (us4*)(O + ((size_t)f * 64 + lane) * 8);
    dst[0] = (us4){t[0], t[1], t[2], t[3]};
    dst[1] = (us4){t[4], t[5], t[6], t[7]};
}

// ---------------- CSR build ----------------
__global__ __launch_bounds__(256) void hist_kernel(
    const int* __restrict__ dst, int* __restrict__ deg, int E)
{
    int e = blockIdx.x * 256 + threadIdx.x;
    if (e < E) atomicAdd(&deg[dst[e]], 1);
}

__global__ __launch_bounds__(256) void deg_blocksum(
    const int* __restrict__ deg, int* __restrict__ bsum, int Nn)
{
    __shared__ int ws[4];
    int b = blockIdx.x, t = threadIdx.x, lane = t & 63, w = t >> 6;
    int i0 = b * 1024 + t * 4;
    int s = 0;
    if (i0 + 3 < Nn) { int4 v = *(const int4*)(deg + i0); s = v.x + v.y + v.z + v.w; }
    else { for (int j = 0; j < 4; ++j) if (i0 + j < Nn) s += deg[i0 + j]; }
    #pragma unroll
    for (int o = 32; o >= 1; o >>= 1) s += __shfl_xor(s, o, 64);
    if (lane == 0) ws[w] = s;
    __syncthreads();
    if (t == 0) bsum[b] = ws[0] + ws[1] + ws[2] + ws[3];
}

__global__ __launch_bounds__(64) void scan_bsums(
    const int* __restrict__ bsum, int* __restrict__ boff, int nb,
    int* __restrict__ offs, int Nn)
{
    int lane = threadIdx.x;
    int v = (lane < nb) ? bsum[lane] : 0;
    int inc = v;
    #pragma unroll
    for (int o = 1; o < 64; o <<= 1) { int n = __shfl_up(inc, o, 64); if (lane >= o) inc += n; }
    if (lane < nb) boff[lane] = inc - v;
    if (lane == 63) offs[Nn] = inc;
}

__global__ __launch_bounds__(256) void scan_final(
    const int* __restrict__ deg, const int* __restrict__ boff,
    int* __restrict__ offs, int Nn)
{
    __shared__ int wsum[4];
    int b = blockIdx.x, t = threadIdx.x, lane = t & 63, w = t >> 6;
    int i0 = b * 1024 + t * 4;
    int a = 0, bb = 0, c = 0, d = 0;
    if (i0 + 3 < Nn) { int4 v = *(const int4*)(deg + i0); a = v.x; bb = v.y; c = v.z; d = v.w; }
    else {
        if (i0     < Nn) a  = deg[i0];
        if (i0 + 1 < Nn) bb = deg[i0 + 1];
        if (i0 + 2 < Nn) c  = deg[i0 + 2];
    }
    int tot = a + bb + c + d, inc = tot;
    #pragma unroll
    for (int o = 1; o < 64; o <<= 1) { int n = __shfl_up(inc, o, 64); if (lane >= o) inc += n; }
    if (lane == 63) wsum[w] = inc;
    __syncthreads();
    int wbase = 0;
    #pragma unroll
    for (int j = 0; j < 4; ++j) if (j < w) wbase += wsum[j];
    int excl = boff[b] + wbase + inc - tot;
    if (i0     < Nn) offs[i0]     = excl;
    if (i0 + 1 < Nn) offs[i0 + 1] = excl + a;
    if (i0 + 2 < Nn) offs[i0 + 2] = excl + a + bb;
    if (i0 + 3 < Nn) offs[i0 + 3] = excl + a + bb + c;
}

__global__ __launch_bounds__(256) void fill_kernel(
    const int* __restrict__ dst, const int* __restrict__ offs,
    int* __restrict__ cursor, int* __restrict__ eids, int E)
{
    int e = blockIdx.x * 256 + threadIdx.x;
    if (e < E) {
        int d = dst[e];
        int p = atomicAdd(&cursor[d], 1);
        eids[offs[d] + p] = e;
    }
}

// --------- aggregate: aggb[n] = bf16( x[n] + sum relu(x[src]+ea) ), 2 edges/wave ---------
__global__ __launch_bounds__(256) void aggregate_csr(
    const float* __restrict__ x, const float* __restrict__ ea,
    const int* __restrict__ src, const int* __restrict__ offs,
    const int* __restrict__ eids, unsigned short* __restrict__ aggb, int Nn)
{
    int node = blockIdx.x * 4 + (threadIdx.x >> 6);
    if (node >= Nn) return;
    int lane = threadIdx.x & 63;
    int half = lane >> 5;
    int c4 = (lane & 31) * 4;
    int beg = offs[node], end = offs[node + 1];
    float4 acc = {0.f, 0.f, 0.f, 0.f};
    if (half == 0) acc = *(const float4*)(x + (size_t)node * DD + c4);
    for (int cb = beg; cb < end; cb += 64) {
        int cnt = min(64, end - cb);
        int myeid = 0, mysrc = 0;
        if (lane < cnt) { myeid = eids[cb + lane]; mysrc = src[myeid]; }
        for (int i = 0; i < cnt; i += 2) {
            int idx = i + half;
            if (idx < cnt) {
                int e = __shfl(myeid, idx, 64);
                int s = __shfl(mysrc, idx, 64);
                float4 ev = *(const float4*)(ea + (size_t)e * DD + c4);
                float4 xv = *(const float4*)(x + (size_t)s * DD + c4);
                acc.x += fmaxf(xv.x + ev.x, 0.f);
                acc.y += fmaxf(xv.y + ev.y, 0.f);
                acc.z += fmaxf(xv.z + ev.z, 0.f);
                acc.w += fmaxf(xv.w + ev.w, 0.f);
            }
        }
    }
    acc.x += __shfl_xor(acc.x, 32, 64);
    acc.y += __shfl_xor(acc.y, 32, 64);
    acc.z += __shfl_xor(acc.z, 32, 64);
    acc.w += __shfl_xor(acc.w, 32, 64);
    if (half == 0) {
        us4 o = {f2bf(acc.x), f2bf(acc.y), f2bf(acc.z), f2bf(acc.w)};
        *(us4*)(aggb + (size_t)node * DD + c4) = o;
    }
}

// ------------- GEMM A (MFMA): mid = bf16(relu(LN(A@W1a + b))), A[N,128], out[N,256] -------------
// swapped operands: lane owns row rb+(lane&15) (+16), cols cf*16+(lane>>4)*4+reg
__global__ __launch_bounds__(256) void gemm_a_mfma(
    const unsigned short* __restrict__ A, const unsigned short* __restrict__ Wf,
    const float* __restrict__ bias, const float* __restrict__ g,
    const float* __restrict__ be, unsigned short* __restrict__ out, int Nn)
{
    const int lane = threadIdx.x & 63;
    const int wid = threadIdx.x >> 6;
    const int rb = (blockIdx.x * 4 + wid) * 32;
    const int rlo = lane & 15, khi = lane >> 4;
    const int r0 = rb + rlo, r1 = rb + 16 + rlo;
    const size_t rr0 = (size_t)min(r0, Nn - 1), rr1 = (size_t)min(r1, Nn - 1);

    bf16x8 aF0[4], aF1[4];
    #pragma unroll
    for (int ks = 0; ks < 4; ++ks) {
        aF0[ks] = *(const bf16x8*)(A + rr0 * DD + ks * 32 + khi * 8);
        aF1[ks] = *(const bf16x8*)(A + rr1 * DD + ks * 32 + khi * 8);
    }
    f32x4 acc0[16], acc1[16];
    #pragma unroll
    for (int cf = 0; cf < 16; ++cf) {
        acc0[cf] = (f32x4){0.f, 0.f, 0.f, 0.f};
        acc1[cf] = (f32x4){0.f, 0.f, 0.f, 0.f};
    }
    #pragma unroll
    for (int cf = 0; cf < 16; ++cf) {
        #pragma unroll
        for (int ks = 0; ks < 4; ++ks) {
            bf16x8 wv = *(const bf16x8*)(Wf + ((size_t)(cf * 4 + ks) * 64 + lane) * 8);
            acc0[cf] = MFMA16(wv, aF0[ks], acc0[cf]);
            acc1[cf] = MFMA16(wv, aF1[ks], acc1[cf]);
        }
    }
    float s0 = 0.f, q0 = 0.f, s1 = 0.f, q1 = 0.f;
    #pragma unroll
    for (int cf = 0; cf < 16; ++cf) {
        float4 bv = *(const float4*)(bias + cf * 16 + khi * 4);
        acc0[cf].x += bv.x; acc0[cf].y += bv.y; acc0[cf].z += bv.z; acc0[cf].w += bv.w;
        acc1[cf].x += bv.x; acc1[cf].y += bv.y; acc1[cf].z += bv.z; acc1[cf].w += bv.w;
        s0 += acc0[cf].x + acc0[cf].y + acc0[cf].z + acc0[cf].w;
        q0 += acc0[cf].x * acc0[cf].x + acc0[cf].y * acc0[cf].y + acc0[cf].z * acc0[cf].z + acc0[cf].w * acc0[cf].w;
        s1 += acc1[cf].x + acc1[cf].y + acc1[cf].z + acc1[cf].w;
        q1 += acc1[cf].x * acc1[cf].x + acc1[cf].y * acc1[cf].y + acc1[cf].z * acc1[cf].z + acc1[cf].w * acc1[cf].w;
    }
    s0 += __shfl_xor(s0, 16, 64); s0 += __shfl_xor(s0, 32, 64);
    q0 += __shfl_xor(q0, 16, 64); q0 += __shfl_xor(q0, 32, 64);
    s1 += __shfl_xor(s1, 16, 64); s1 += __shfl_xor(s1, 32, 64);
    q1 += __shfl_xor(q1, 16, 64); q1 += __shfl_xor(q1, 32, 64);
    const float m0 = s0 * (1.f / D2), m1 = s1 * (1.f / D2);
    const float rs0 = rsqrtf(q0 * (1.f / D2) - m0 * m0 + 1e-5f);
    const float rs1 = rsqrtf(q1 * (1.f / D2) - m1 * m1 + 1e-5f);
    #pragma unroll
    for (int cf = 0; cf < 16; ++cf) {
        float4 gv = *(const float4*)(g + cf * 16 + khi * 4);
        float4 ev = *(const float4*)(be + cf * 16 + khi * 4);
        if (r0 < Nn) {
            us4 o = {f2bf(fmaxf((acc0[cf].x - m0) * rs0 * gv.x + ev.x, 0.f)),
                     f2bf(fmaxf((acc0[cf].y - m0) * rs0 * gv.y + ev.y, 0.f)),
                     f2bf(fmaxf((acc0[cf].z - m0) * rs0 * gv.z + ev.z, 0.f)),
                     f2bf(fmaxf((acc0[cf].w - m0) * rs0 * gv.w + ev.w, 0.f))};
            *(us4*)(out + (size_t)r0 * D2 + cf * 16 + khi * 4) = o;
        }
        if (r1 < Nn) {
            us4 o = {f2bf(fmaxf((acc1[cf].x - m1) * rs1 * gv.x + ev.x, 0.f)),
                     f2bf(fmaxf((acc1[cf].y - m1) * rs1 * gv.y + ev.y, 0.f)),
                     f2bf(fmaxf((acc1[cf].z - m1) * rs1 * gv.z + ev.z, 0.f)),
                     f2bf(fmaxf((acc1[cf].w - m1) * rs1 * gv.w + ev.w, 0.f))};
            *(us4*)(out + (size_t)r1 * D2 + cf * 16 + khi * 4) = o;
        }
    }
}

// ------------- GEMM B (MFMA): h = LN(relu(X@W + b)); X[N,256], out[N,128] f32 + bf16 -------------
__global__ __launch_bounds__(256) void gemm_b_mfma(
    const unsigned short* __restrict__ X, const unsigned short* __restrict__ Wf,
    const float* __restrict__ bias, const float* __restrict__ g,
    const float* __restrict__ be, float* __restrict__ outf,
    unsigned short* __restrict__ outb, int Nn)
{
    const int lane = threadIdx.x & 63;
    const int wid = threadIdx.x >> 6;
    const int rb = (blockIdx.x * 4 + wid) * 32;
    const int rlo = lane & 15, khi = lane >> 4;
    const int r0 = rb + rlo, r1 = rb + 16 + rlo;
    const size_t rr0 = (size_t)min(r0, Nn - 1), rr1 = (size_t)min(r1, Nn - 1);

    bf16x8 aF0[8], aF1[8];
    #pragma unroll
    for (int ks = 0; ks < 8; ++ks) {
        aF0[ks] = *(const bf16x8*)(X + rr0 * D2 + ks * 32 + khi * 8);
        aF1[ks] = *(const bf16x8*)(X + rr1 * D2 + ks * 32 + khi * 8);
    }
    f32x4 acc0[8], acc1[8];
    #pragma unroll
    for (int cf = 0; cf < 8; ++cf) {
        acc0[cf] = (f32x4){0.f, 0.f, 0.f, 0.f};
        acc1[cf] = (f32x4){0.f, 0.f, 0.f, 0.f};
    }
    #pragma unroll
    for (int cf = 0; cf < 8; ++cf) {
        #pragma unroll
        for (int ks = 0; ks < 8; ++ks) {
            bf16x8 wv = *(const bf16x8*)(Wf + ((size_t)(cf * 8 + ks) * 64 + lane) * 8);
            acc0[cf] = MFMA16(wv, aF0[ks], acc0[cf]);
            acc1[cf] = MFMA16(wv, aF1[ks], acc1[cf]);
        }
    }
    float s0 = 0.f, q0 = 0.f, s1 = 0.f, q1 = 0.f;
    #pragma unroll
    for (int cf = 0; cf < 8; ++cf) {
        float4 bv = *(const float4*)(bias + cf * 16 + khi * 4);
        acc0[cf].x = fmaxf(acc0[cf].x + bv.x, 0.f); acc0[cf].y = fmaxf(acc0[cf].y + bv.y, 0.f);
        acc0[cf].z = fmaxf(acc0[cf].z + bv.z, 0.f); acc0[cf].w = fmaxf(acc0[cf].w + bv.w, 0.f);
        acc1[cf].x = fmaxf(acc1[cf].x + bv.x, 0.f); acc1[cf].y = fmaxf(acc1[cf].y + bv.y, 0.f);
        acc1[cf].z = fmaxf(acc1[cf].z + bv.z, 0.f); acc1[cf].w = fmaxf(acc1[cf].w + bv.w, 0.f);
        s0 += acc0[cf].x + acc0[cf].y + acc0[cf].z + acc0[cf].w;
        q0 += acc0[cf].x * acc0[cf].x + acc0[cf].y * acc0[cf].y + acc0[cf].z * acc0[cf].z + acc0[cf].w * acc0[cf].w;
        s1 += acc1[cf].x + acc1[cf].y + acc1[cf].z + acc1[cf].w;
        q1 += acc1[cf].x * acc1[cf].x + acc1[cf].y * acc1[cf].y + acc1[cf].z * acc1[cf].z + acc1[cf].w * acc1[cf].w;
    }
    s0 += __shfl_xor(s0, 16, 64); s0 += __shfl_xor(s0, 32, 64);
    q0 += __shfl_xor(q0, 16, 64); q0 += __shfl_xor(q0, 32, 64);
    s1 += __shfl_xor(s1, 16, 64); s1 += __shfl_xor(s1, 32, 64);
    q1 += __shfl_xor(q1, 16, 64); q1 += __shfl_xor(q1, 32, 64);
    const float m0 = s0 * (1.f / DD), m1 = s1 * (1.f / DD);
    const float rs0 = rsqrtf(q0 * (1.f / DD) - m0 * m0 + 1e-5f);
    const float rs1 = rsqrtf(q1 * (1.f / DD) - m1 * m1 + 1e-5f);
    #pragma unroll
    for (int cf = 0; cf < 8; ++cf) {
        float4 gv = *(const float4*)(g + cf * 16 + khi * 4);
        float4 ev = *(const float4*)(be + cf * 16 + khi * 4);
        if (r0 < Nn) {
            float4 o;
            o.x = (acc0[cf].x - m0) * rs0 * gv.x + ev.x;
            o.y = (acc0[cf].y - m0) * rs0 * gv.y + ev.y;
            o.z = (acc0[cf].z - m0) * rs0 * gv.z + ev.z;
            o.w = (acc0[cf].w - m0) * rs0 * gv.w + ev.w;
            *(float4*)(outf + (size_t)r0 * DD + cf * 16 + khi * 4) = o;
            us4 ob = {f2bf(o.x), f2bf(o.y), f2bf(o.z), f2bf(o.w)};
            *(us4*)(outb + (size_t)r0 * DD + cf * 16 + khi * 4) = ob;
        }
        if (r1 < Nn) {
            float4 o;
            o.x = (acc1[cf].x - m1) * rs1 * gv.x + ev.x;
            o.y = (acc1[cf].y - m1) * rs1 * gv.y + ev.y;
            o.z = (acc1[cf].z - m1) * rs1 * gv.z + ev.z;
            o.w = (acc1[cf].w - m1) * rs1 * gv.w + ev.w;
            *(float4*)(outf + (size_t)r1 * DD + cf * 16 + khi * 4) = o;
            us4 ob = {f2bf(o.x), f2bf(o.y), f2bf(o.z), f2bf(o.w)};
            *(us4*)(outb + (size_t)r1 * DD + cf * 16 + khi * 4) = ob;
        }
    }
}

// ------------- final GEMM (MFMA): out = relu([h1|h2]@Wl + bl), fp32 out -------------
__global__ __launch_bounds__(256) void gemm_final_mfma(
    const unsigned short* __restrict__ A1, const unsigned short* __restrict__ A2,
    const unsigned short* __restrict__ Wf, const float* __restrict__ bias,
    float* __restrict__ out, int Nn)
{
    const int lane = threadIdx.x & 63;
    const int wid = threadIdx.x >> 6;
    const int rb = (blockIdx.x * 4 + wid) * 32;
    const int rlo = lane & 15, khi = lane >> 4;
    const int r0 = rb + rlo, r1 = rb + 16 + rlo;
    const size_t rr0 = (size_t)min(r0, Nn - 1), rr1 = (size_t)min(r1, Nn - 1);

    bf16x8 aF0[8], aF1[8];
    #pragma unroll
    for (int ks = 0; ks < 4; ++ks) {
        aF0[ks]     = *(const bf16x8*)(A1 + rr0 * DD + ks * 32 + khi * 8);
        aF0[ks + 4] = *(const bf16x8*)(A2 + rr0 * DD + ks * 32 + khi * 8);
        aF1[ks]     = *(const bf16x8*)(A1 + rr1 * DD + ks * 32 + khi * 8);
        aF1[ks + 4] = *(const bf16x8*)(A2 + rr1 * DD + ks * 32 + khi * 8);
    }
    f32x4 acc0[8], acc1[8];
    #pragma unroll
    for (int cf = 0; cf < 8; ++cf) {
        acc0[cf] = (f32x4){0.f, 0.f, 0.f, 0.f};
        acc1[cf] = (f32x4){0.f, 0.f, 0.f, 0.f};
    }
    #pragma unroll
    for (int cf = 0; cf < 8; ++cf) {
        #pragma unroll
        for (int ks = 0; ks < 8; ++ks) {
            bf16x8 wv = *(const bf16x8*)(Wf + ((size_t)(cf * 8 + ks) * 64 + lane) * 8);
            acc0[cf] = MFMA16(wv, aF0[ks], acc0[cf]);
            acc1[cf] = MFMA16(wv, aF1[ks], acc1[cf]);
        }
    }
    #pragma unroll
    for (int cf = 0; cf < 8; ++cf) {
        float4 bv = *(const float4*)(bias + cf * 16 + khi * 4);
        if (r0 < Nn) {
            float4 o;
            o.x = fmaxf(acc0[cf].x + bv.x, 0.f);
            o.y = fmaxf(acc0[cf].y + bv.y, 0.f);
            o.z = fmaxf(acc0[cf].z + bv.z, 0.f);
            o.w = fmaxf(acc0[cf].w + bv.w, 0.f);
            *(float4*)(out + (size_t)r0 * DD + cf * 16 + khi * 4) = o;
        }
        if (r1 < Nn) {
            float4 o;
            o.x = fmaxf(acc1[cf].x + bv.x, 0.f);
            o.y = fmaxf(acc1[cf].y + bv.y, 0.f);
            o.z = fmaxf(acc1[cf].z + bv.z, 0.f);
            o.w = fmaxf(acc1[cf].w + bv.w, 0.f);
            *(float4*)(out + (size_t)r1 * DD + cf * 16 + khi * 4) = o;
        }
    }
}

extern "C" void kernel_launch(void* const* d_in, const int* in_sizes, int n_in,
                              void* d_out, int out_size, void* d_ws, size_t ws_size,
                              hipStream_t stream)
{
    const float* x    = (const float*)d_in[0];
    const int*   ei   = (const int*)d_in[1];
    const float* ea   = (const float*)d_in[2];
    const float* w1a  = (const float*)d_in[4];
    const float* b1a  = (const float*)d_in[5];
    const float* g1a  = (const float*)d_in[6];
    const float* be1a = (const float*)d_in[7];
    const float* w1b  = (const float*)d_in[8];
    const float* b1b  = (const float*)d_in[9];
    const float* w2a  = (const float*)d_in[10];
    const float* b2a  = (const float*)d_in[11];
    const float* g2a  = (const float*)d_in[12];
    const float* be2a = (const float*)d_in[13];
    const float* w2b  = (const float*)d_in[14];
    const float* b2b  = (const float*)d_in[15];
    const float* ng1  = (const float*)d_in[16];
    const float* nb1  = (const float*)d_in[17];
    const float* ng2  = (const float*)d_in[18];
    const float* nb2  = (const float*)d_in[19];
    const float* wl   = (const float*)d_in[20];
    const float* bl   = (const float*)d_in[21];

    const int N = in_sizes[0] / DD;
    const int E = in_sizes[1] / 2;
    const int* src = ei;
    const int* dst = ei + E;

    char* wp = (char*)d_ws;
    auto alloc = [&](size_t bytes) { void* p = wp; wp += (bytes + 255) & ~(size_t)255; return p; };
    unsigned short* aggb = (unsigned short*)alloc((size_t)N * DD * 2);
    unsigned short* mid  = (unsigned short*)alloc((size_t)N * D2 * 2);
    float*          h1f  = (float*)alloc((size_t)N * DD * 4);
    unsigned short* h1b  = (unsigned short*)alloc((size_t)N * DD * 2);
    float*          h2f  = (float*)alloc((size_t)N * DD * 4);
    unsigned short* h2b  = (unsigned short*)alloc((size_t)N * DD * 2);
    unsigned short* WfA1 = (unsigned short*)alloc(32768 * 2);
    unsigned short* WfB1 = (unsigned short*)alloc(32768 * 2);
    unsigned short* WfA2 = (unsigned short*)alloc(32768 * 2);
    unsigned short* WfB2 = (unsigned short*)alloc(32768 * 2);
    unsigned short* WfL  = (unsigned short*)alloc(32768 * 2);
    int* deg    = (int*)alloc((size_t)N * 4);
    int* offs   = (int*)alloc((size_t)(N + 1) * 4);
    int* cursor = (int*)alloc((size_t)N * 4);
    int* bsum   = (int*)alloc(64 * 4);
    int* boff   = (int*)alloc(64 * 4);
    int* eids   = (int*)alloc((size_t)E * 4);

    const int nb = (N + 1023) / 1024;
    const int gE = (E + 255) / 256;
    const int gagg = (N + 3) / 4;
    const int gg = (N + 127) / 128;

    hipMemsetAsync(deg, 0, (size_t)N * 4, stream);
    hipMemsetAsync(cursor, 0, (size_t)N * 4, stream);
    pack_weights<<<320, 64, 0, stream>>>(w1a, w1b, w2a, w2b, wl, WfA1, WfB1, WfA2, WfB2, WfL);
    hist_kernel<<<gE, 256, 0, stream>>>(dst, deg, E);
    deg_blocksum<<<nb, 256, 0, stream>>>(deg, bsum, N);
    scan_bsums<<<1, 64, 0, stream>>>(bsum, boff, nb, offs, N);
    scan_final<<<nb, 256, 0, stream>>>(deg, boff, offs, N);
    fill_kernel<<<gE, 256, 0, stream>>>(dst, offs, cursor, eids, E);

    // ---- conv1 ----
    aggregate_csr<<<gagg, 256, 0, stream>>>(x, ea, src, offs, eids, aggb, N);
    gemm_a_mfma<<<gg, 256, 0, stream>>>(aggb, WfA1, b1a, g1a, be1a, mid, N);
    gemm_b_mfma<<<gg, 256, 0, stream>>>(mid, WfB1, b1b, ng1, nb1, h1f, h1b, N);

    // ---- conv2 ----
    aggregate_csr<<<gagg, 256, 0, stream>>>(h1f, ea, src, offs, eids, aggb, N);
    gemm_a_mfma<<<gg, 256, 0, stream>>>(aggb, WfA2, b2a, g2a, be2a, mid, N);
    gemm_b_mfma<<<gg, 256, 0, stream>>>(mid, WfB2, b2b, ng2, nb2, h2f, h2b, N);

    // ---- final ----
    gemm_final_mfma<<<gg, 256, 0, stream>>>(h1b, h2b, WfL, bl, (float*)d_out, N);
}

// Round 5
// 360.758 us; speedup vs baseline: 6.5343x; 1.1784x over previous
//
#include <hip/hip_runtime.h>

#define DD 128
#define D2 256

typedef __attribute__((ext_vector_type(8))) short bf16x8;
typedef __attribute__((ext_vector_type(8))) unsigned short us8;
typedef __attribute__((ext_vector_type(4))) float f32x4;
typedef __attribute__((ext_vector_type(4))) unsigned short us4;

#define MFMA16(a,b,c) __builtin_amdgcn_mfma_f32_16x16x32_bf16(a,b,c,0,0,0)

__device__ __forceinline__ unsigned short f2bf(float f) {
    unsigned int u = __float_as_uint(f);
    u += 0x7FFF + ((u >> 16) & 1);
    return (unsigned short)(u >> 16);
}
__device__ __forceinline__ float bf2f(unsigned short b) {
    return __uint_as_float(((unsigned int)b) << 16);
}

// ---------------- x -> bf16 convert (8 elems/thread) ----------------
__global__ __launch_bounds__(256) void cvt_bf16_8(
    const float* __restrict__ in, unsigned short* __restrict__ out, int n8)
{
    int i = blockIdx.x * 256 + threadIdx.x;
    if (i >= n8) return;
    f32x4 a = *(const f32x4*)(in + (size_t)i * 8);
    f32x4 b = *(const f32x4*)(in + (size_t)i * 8 + 4);
    us8 o = {f2bf(a.x), f2bf(a.y), f2bf(a.z), f2bf(a.w),
             f2bf(b.x), f2bf(b.y), f2bf(b.z), f2bf(b.w)};
    *(us8*)(out + (size_t)i * 8) = o;
}

// ---------------- weight pre-pack: fp32 [K][Nc] -> bf16 frag-linear ----------------
__global__ __launch_bounds__(64) void pack_weights(
    const float* __restrict__ w1a, const float* __restrict__ w1b,
    const float* __restrict__ w2a, const float* __restrict__ w2b,
    const float* __restrict__ wl,
    unsigned short* __restrict__ o1a, unsigned short* __restrict__ o1b,
    unsigned short* __restrict__ o2a, unsigned short* __restrict__ o2b,
    unsigned short* __restrict__ ol)
{
    int widx = blockIdx.x >> 6;
    int f = blockIdx.x & 63;
    int lane = threadIdx.x;
    const float* W; unsigned short* O; int nks, Nc;
    switch (widx) {
        case 0: W = w1a; O = o1a; nks = 4; Nc = 256; break;
        case 1: W = w1b; O = o1b; nks = 8; Nc = 128; break;
        case 2: W = w2a; O = o2a; nks = 4; Nc = 256; break;
        case 3: W = w2b; O = o2b; nks = 8; Nc = 128; break;
        default: W = wl; O = ol;  nks = 8; Nc = 128; break;
    }
    int cf = f / nks, ks = f % nks;
    int col = cf * 16 + (lane & 15);
    int k0 = ks * 32 + (lane >> 4) * 8;
    unsigned short t[8];
    #pragma unroll
    for (int j = 0; j < 8; ++j) t[j] = f2bf(W[(size_t)(k0 + j) * Nc + col]);
    us4* dst = (us4*)(O + ((size_t)f * 64 + lane) * 8);
    dst[0] = (us4){t[0], t[1], t[2], t[3]};
    dst[1] = (us4){t[4], t[5], t[6], t[7]};
}

// ---------------- CSR build ----------------
__global__ __launch_bounds__(256) void hist_kernel(
    const int* __restrict__ dst, int* __restrict__ deg, int E)
{
    int e = blockIdx.x * 256 + threadIdx.x;
    if (e < E) atomicAdd(&deg[dst[e]], 1);
}

__global__ __launch_bounds__(256) void deg_blocksum(
    const int* __restrict__ deg, int* __restrict__ bsum, int Nn)
{
    __shared__ int ws[4];
    int b = blockIdx.x, t = threadIdx.x, lane = t & 63, w = t >> 6;
    int i0 = b * 1024 + t * 4;
    int s = 0;
    if (i0 + 3 < Nn) { int4 v = *(const int4*)(deg + i0); s = v.x + v.y + v.z + v.w; }
    else { for (int j = 0; j < 4; ++j) if (i0 + j < Nn) s += deg[i0 + j]; }
    #pragma unroll
    for (int o = 32; o >= 1; o >>= 1) s += __shfl_xor(s, o, 64);
    if (lane == 0) ws[w] = s;
    __syncthreads();
    if (t == 0) bsum[b] = ws[0] + ws[1] + ws[2] + ws[3];
}

__global__ __launch_bounds__(64) void scan_bsums(
    const int* __restrict__ bsum, int* __restrict__ boff, int nb,
    int* __restrict__ offs, int Nn)
{
    int lane = threadIdx.x;
    int v = (lane < nb) ? bsum[lane] : 0;
    int inc = v;
    #pragma unroll
    for (int o = 1; o < 64; o <<= 1) { int n = __shfl_up(inc, o, 64); if (lane >= o) inc += n; }
    if (lane < nb) boff[lane] = inc - v;
    if (lane == 63) offs[Nn] = inc;
}

__global__ __launch_bounds__(256) void scan_final(
    const int* __restrict__ deg, const int* __restrict__ boff,
    int* __restrict__ offs, int Nn)
{
    __shared__ int wsum[4];
    int b = blockIdx.x, t = threadIdx.x, lane = t & 63, w = t >> 6;
    int i0 = b * 1024 + t * 4;
    int a = 0, bb = 0, c = 0, d = 0;
    if (i0 + 3 < Nn) { int4 v = *(const int4*)(deg + i0); a = v.x; bb = v.y; c = v.z; d = v.w; }
    else {
        if (i0     < Nn) a  = deg[i0];
        if (i0 + 1 < Nn) bb = deg[i0 + 1];
        if (i0 + 2 < Nn) c  = deg[i0 + 2];
    }
    int tot = a + bb + c + d, inc = tot;
    #pragma unroll
    for (int o = 1; o < 64; o <<= 1) { int n = __shfl_up(inc, o, 64); if (lane >= o) inc += n; }
    if (lane == 63) wsum[w] = inc;
    __syncthreads();
    int wbase = 0;
    #pragma unroll
    for (int j = 0; j < 4; ++j) if (j < w) wbase += wsum[j];
    int excl = boff[b] + wbase + inc - tot;
    if (i0     < Nn) offs[i0]     = excl;
    if (i0 + 1 < Nn) offs[i0 + 1] = excl + a;
    if (i0 + 2 < Nn) offs[i0 + 2] = excl + a + bb;
    if (i0 + 3 < Nn) offs[i0 + 3] = excl + a + bb + c;
}

__global__ __launch_bounds__(256) void fill_kernel(
    const int* __restrict__ dst, const int* __restrict__ offs,
    int* __restrict__ cursor, int* __restrict__ eids, int E)
{
    int e = blockIdx.x * 256 + threadIdx.x;
    if (e < E) {
        int d = dst[e];
        int p = atomicAdd(&cursor[d], 1);
        eids[offs[d] + p] = e;
    }
}

// --------- aggregate conv1: aggb[n] = bf16( x[n] + sum relu(x[src]+ea) ) ---------
// also converts ea -> eab (bf16) inline. 4 edges in flight (16-lane groups).
__global__ __launch_bounds__(256) void aggregate_conv1(
    const unsigned short* __restrict__ xb, const float* __restrict__ ea,
    unsigned short* __restrict__ eab, const int* __restrict__ src,
    const int* __restrict__ offs, const int* __restrict__ eids,
    unsigned short* __restrict__ aggb, int Nn)
{
    int node = blockIdx.x * 4 + (threadIdx.x >> 6);
    if (node >= Nn) return;
    int lane = threadIdx.x & 63;
    int g = lane >> 4, c8 = (lane & 15) * 8;
    int beg = offs[node], end = offs[node + 1];
    float acc[8] = {};
    if (g == 0) {
        us8 xv = *(const us8*)(xb + (size_t)node * DD + c8);
        #pragma unroll
        for (int j = 0; j < 8; ++j) acc[j] = bf2f(xv[j]);
    }
    for (int cb = beg; cb < end; cb += 64) {
        int cnt = min(64, end - cb);
        int myeid = 0, mysrc = 0;
        if (lane < cnt) { myeid = eids[cb + lane]; mysrc = src[myeid]; }
        for (int i = 0; i < cnt; i += 4) {
            int idx = i + g;
            bool act = idx < cnt;
            int e = __shfl(myeid, idx, 64);
            int s = __shfl(mysrc, idx, 64);
            if (act) {
                const float* ep = ea + (size_t)e * DD + c8;
                f32x4 e0 = __builtin_nontemporal_load((const f32x4*)ep);
                f32x4 e1 = __builtin_nontemporal_load((const f32x4*)(ep + 4));
                us8 xv = *(const us8*)(xb + (size_t)s * DD + c8);
                us8 eb = {f2bf(e0.x), f2bf(e0.y), f2bf(e0.z), f2bf(e0.w),
                          f2bf(e1.x), f2bf(e1.y), f2bf(e1.z), f2bf(e1.w)};
                __builtin_nontemporal_store(eb, (us8*)(eab + (size_t)e * DD + c8));
                acc[0] += fmaxf(bf2f(xv[0]) + e0.x, 0.f);
                acc[1] += fmaxf(bf2f(xv[1]) + e0.y, 0.f);
                acc[2] += fmaxf(bf2f(xv[2]) + e0.z, 0.f);
                acc[3] += fmaxf(bf2f(xv[3]) + e0.w, 0.f);
                acc[4] += fmaxf(bf2f(xv[4]) + e1.x, 0.f);
                acc[5] += fmaxf(bf2f(xv[5]) + e1.y, 0.f);
                acc[6] += fmaxf(bf2f(xv[6]) + e1.z, 0.f);
                acc[7] += fmaxf(bf2f(xv[7]) + e1.w, 0.f);
            }
        }
    }
    #pragma unroll
    for (int j = 0; j < 8; ++j) {
        acc[j] += __shfl_xor(acc[j], 16, 64);
        acc[j] += __shfl_xor(acc[j], 32, 64);
    }
    if (g == 0) {
        us8 o = {f2bf(acc[0]), f2bf(acc[1]), f2bf(acc[2]), f2bf(acc[3]),
                 f2bf(acc[4]), f2bf(acc[5]), f2bf(acc[6]), f2bf(acc[7])};
        *(us8*)(aggb + (size_t)node * DD + c8) = o;
    }
}

// --------- aggregate conv2: all-bf16 inputs (h1b gather + eab stream) ---------
__global__ __launch_bounds__(256) void aggregate_conv2(
    const unsigned short* __restrict__ hb, const unsigned short* __restrict__ eab,
    const int* __restrict__ src, const int* __restrict__ offs,
    const int* __restrict__ eids, unsigned short* __restrict__ aggb, int Nn)
{
    int node = blockIdx.x * 4 + (threadIdx.x >> 6);
    if (node >= Nn) return;
    int lane = threadIdx.x & 63;
    int g = lane >> 4, c8 = (lane & 15) * 8;
    int beg = offs[node], end = offs[node + 1];
    float acc[8] = {};
    if (g == 0) {
        us8 xv = *(const us8*)(hb + (size_t)node * DD + c8);
        #pragma unroll
        for (int j = 0; j < 8; ++j) acc[j] = bf2f(xv[j]);
    }
    for (int cb = beg; cb < end; cb += 64) {
        int cnt = min(64, end - cb);
        int myeid = 0, mysrc = 0;
        if (lane < cnt) { myeid = eids[cb + lane]; mysrc = src[myeid]; }
        for (int i = 0; i < cnt; i += 4) {
            int idx = i + g;
            bool act = idx < cnt;
            int e = __shfl(myeid, idx, 64);
            int s = __shfl(mysrc, idx, 64);
            if (act) {
                us8 ev = __builtin_nontemporal_load((const us8*)(eab + (size_t)e * DD + c8));
                us8 xv = *(const us8*)(hb + (size_t)s * DD + c8);
                #pragma unroll
                for (int j = 0; j < 8; ++j)
                    acc[j] += fmaxf(bf2f(xv[j]) + bf2f(ev[j]), 0.f);
            }
        }
    }
    #pragma unroll
    for (int j = 0; j < 8; ++j) {
        acc[j] += __shfl_xor(acc[j], 16, 64);
        acc[j] += __shfl_xor(acc[j], 32, 64);
    }
    if (g == 0) {
        us8 o = {f2bf(acc[0]), f2bf(acc[1]), f2bf(acc[2]), f2bf(acc[3]),
                 f2bf(acc[4]), f2bf(acc[5]), f2bf(acc[6]), f2bf(acc[7])};
        *(us8*)(aggb + (size_t)node * DD + c8) = o;
    }
}

// ------------- GEMM A (MFMA): mid = bf16(relu(LN(A@W + b))), A[N,128] -> out[N,256] -------------
__global__ __launch_bounds__(256) void gemm_a_mfma(
    const unsigned short* __restrict__ A, const unsigned short* __restrict__ Wf,
    const float* __restrict__ bias, const float* __restrict__ g,
    const float* __restrict__ be, unsigned short* __restrict__ out, int Nn)
{
    const int lane = threadIdx.x & 63;
    const int wid = threadIdx.x >> 6;
    const int rb = (blockIdx.x * 4 + wid) * 32;
    const int rlo = lane & 15, khi = lane >> 4;
    const int r0 = rb + rlo, r1 = rb + 16 + rlo;
    const size_t rr0 = (size_t)min(r0, Nn - 1), rr1 = (size_t)min(r1, Nn - 1);

    bf16x8 aF0[4], aF1[4];
    #pragma unroll
    for (int ks = 0; ks < 4; ++ks) {
        aF0[ks] = *(const bf16x8*)(A + rr0 * DD + ks * 32 + khi * 8);
        aF1[ks] = *(const bf16x8*)(A + rr1 * DD + ks * 32 + khi * 8);
    }
    f32x4 acc0[16], acc1[16];
    #pragma unroll
    for (int cf = 0; cf < 16; ++cf) {
        acc0[cf] = (f32x4){0.f, 0.f, 0.f, 0.f};
        acc1[cf] = (f32x4){0.f, 0.f, 0.f, 0.f};
    }
    #pragma unroll
    for (int cf = 0; cf < 16; ++cf) {
        #pragma unroll
        for (int ks = 0; ks < 4; ++ks) {
            bf16x8 wv = *(const bf16x8*)(Wf + ((size_t)(cf * 4 + ks) * 64 + lane) * 8);
            acc0[cf] = MFMA16(wv, aF0[ks], acc0[cf]);
            acc1[cf] = MFMA16(wv, aF1[ks], acc1[cf]);
        }
    }
    float s0 = 0.f, q0 = 0.f, s1 = 0.f, q1 = 0.f;
    #pragma unroll
    for (int cf = 0; cf < 16; ++cf) {
        f32x4 bv = *(const f32x4*)(bias + cf * 16 + khi * 4);
        acc0[cf].x += bv.x; acc0[cf].y += bv.y; acc0[cf].z += bv.z; acc0[cf].w += bv.w;
        acc1[cf].x += bv.x; acc1[cf].y += bv.y; acc1[cf].z += bv.z; acc1[cf].w += bv.w;
        s0 += acc0[cf].x + acc0[cf].y + acc0[cf].z + acc0[cf].w;
        q0 += acc0[cf].x * acc0[cf].x + acc0[cf].y * acc0[cf].y + acc0[cf].z * acc0[cf].z + acc0[cf].w * acc0[cf].w;
        s1 += acc1[cf].x + acc1[cf].y + acc1[cf].z + acc1[cf].w;
        q1 += acc1[cf].x * acc1[cf].x + acc1[cf].y * acc1[cf].y + acc1[cf].z * acc1[cf].z + acc1[cf].w * acc1[cf].w;
    }
    s0 += __shfl_xor(s0, 16, 64); s0 += __shfl_xor(s0, 32, 64);
    q0 += __shfl_xor(q0, 16, 64); q0 += __shfl_xor(q0, 32, 64);
    s1 += __shfl_xor(s1, 16, 64); s1 += __shfl_xor(s1, 32, 64);
    q1 += __shfl_xor(q1, 16, 64); q1 += __shfl_xor(q1, 32, 64);
    const float m0 = s0 * (1.f / D2), m1 = s1 * (1.f / D2);
    const float rs0 = rsqrtf(q0 * (1.f / D2) - m0 * m0 + 1e-5f);
    const float rs1 = rsqrtf(q1 * (1.f / D2) - m1 * m1 + 1e-5f);
    #pragma unroll
    for (int cf = 0; cf < 16; ++cf) {
        f32x4 gv = *(const f32x4*)(g + cf * 16 + khi * 4);
        f32x4 ev = *(const f32x4*)(be + cf * 16 + khi * 4);
        if (r0 < Nn) {
            us4 o = {f2bf(fmaxf((acc0[cf].x - m0) * rs0 * gv.x + ev.x, 0.f)),
                     f2bf(fmaxf((acc0[cf].y - m0) * rs0 * gv.y + ev.y, 0.f)),
                     f2bf(fmaxf((acc0[cf].z - m0) * rs0 * gv.z + ev.z, 0.f)),
                     f2bf(fmaxf((acc0[cf].w - m0) * rs0 * gv.w + ev.w, 0.f))};
            *(us4*)(out + (size_t)r0 * D2 + cf * 16 + khi * 4) = o;
        }
        if (r1 < Nn) {
            us4 o = {f2bf(fmaxf((acc1[cf].x - m1) * rs1 * gv.x + ev.x, 0.f)),
                     f2bf(fmaxf((acc1[cf].y - m1) * rs1 * gv.y + ev.y, 0.f)),
                     f2bf(fmaxf((acc1[cf].z - m1) * rs1 * gv.z + ev.z, 0.f)),
                     f2bf(fmaxf((acc1[cf].w - m1) * rs1 * gv.w + ev.w, 0.f))};
            *(us4*)(out + (size_t)r1 * D2 + cf * 16 + khi * 4) = o;
        }
    }
}

// ------------- GEMM B (MFMA): h = LN(relu(X@W + b)); X[N,256] -> bf16 out[N,128] -------------
__global__ __launch_bounds__(256) void gemm_b_mfma(
    const unsigned short* __restrict__ X, const unsigned short* __restrict__ Wf,
    const float* __restrict__ bias, const float* __restrict__ g,
    const float* __restrict__ be, unsigned short* __restrict__ outb, int Nn)
{
    const int lane = threadIdx.x & 63;
    const int wid = threadIdx.x >> 6;
    const int rb = (blockIdx.x * 4 + wid) * 32;
    const int rlo = lane & 15, khi = lane >> 4;
    const int r0 = rb + rlo, r1 = rb + 16 + rlo;
    const size_t rr0 = (size_t)min(r0, Nn - 1), rr1 = (size_t)min(r1, Nn - 1);

    bf16x8 aF0[8], aF1[8];
    #pragma unroll
    for (int ks = 0; ks < 8; ++ks) {
        aF0[ks] = *(const bf16x8*)(X + rr0 * D2 + ks * 32 + khi * 8);
        aF1[ks] = *(const bf16x8*)(X + rr1 * D2 + ks * 32 + khi * 8);
    }
    f32x4 acc0[8], acc1[8];
    #pragma unroll
    for (int cf = 0; cf < 8; ++cf) {
        acc0[cf] = (f32x4){0.f, 0.f, 0.f, 0.f};
        acc1[cf] = (f32x4){0.f, 0.f, 0.f, 0.f};
    }
    #pragma unroll
    for (int cf = 0; cf < 8; ++cf) {
        #pragma unroll
        for (int ks = 0; ks < 8; ++ks) {
            bf16x8 wv = *(const bf16x8*)(Wf + ((size_t)(cf * 8 + ks) * 64 + lane) * 8);
            acc0[cf] = MFMA16(wv, aF0[ks], acc0[cf]);
            acc1[cf] = MFMA16(wv, aF1[ks], acc1[cf]);
        }
    }
    float s0 = 0.f, q0 = 0.f, s1 = 0.f, q1 = 0.f;
    #pragma unroll
    for (int cf = 0; cf < 8; ++cf) {
        f32x4 bv = *(const f32x4*)(bias + cf * 16 + khi * 4);
        acc0[cf].x = fmaxf(acc0[cf].x + bv.x, 0.f); acc0[cf].y = fmaxf(acc0[cf].y + bv.y, 0.f);
        acc0[cf].z = fmaxf(acc0[cf].z + bv.z, 0.f); acc0[cf].w = fmaxf(acc0[cf].w + bv.w, 0.f);
        acc1[cf].x = fmaxf(acc1[cf].x + bv.x, 0.f); acc1[cf].y = fmaxf(acc1[cf].y + bv.y, 0.f);
        acc1[cf].z = fmaxf(acc1[cf].z + bv.z, 0.f); acc1[cf].w = fmaxf(acc1[cf].w + bv.w, 0.f);
        s0 += acc0[cf].x + acc0[cf].y + acc0[cf].z + acc0[cf].w;
        q0 += acc0[cf].x * acc0[cf].x + acc0[cf].y * acc0[cf].y + acc0[cf].z * acc0[cf].z + acc0[cf].w * acc0[cf].w;
        s1 += acc1[cf].x + acc1[cf].y + acc1[cf].z + acc1[cf].w;
        q1 += acc1[cf].x * acc1[cf].x + acc1[cf].y * acc1[cf].y + acc1[cf].z * acc1[cf].z + acc1[cf].w * acc1[cf].w;
    }
    s0 += __shfl_xor(s0, 16, 64); s0 += __shfl_xor(s0, 32, 64);
    q0 += __shfl_xor(q0, 16, 64); q0 += __shfl_xor(q0, 32, 64);
    s1 += __shfl_xor(s1, 16, 64); s1 += __shfl_xor(s1, 32, 64);
    q1 += __shfl_xor(q1, 16, 64); q1 += __shfl_xor(q1, 32, 64);
    const float m0 = s0 * (1.f / DD), m1 = s1 * (1.f / DD);
    const float rs0 = rsqrtf(q0 * (1.f / DD) - m0 * m0 + 1e-5f);
    const float rs1 = rsqrtf(q1 * (1.f / DD) - m1 * m1 + 1e-5f);
    #pragma unroll
    for (int cf = 0; cf < 8; ++cf) {
        f32x4 gv = *(const f32x4*)(g + cf * 16 + khi * 4);
        f32x4 ev = *(const f32x4*)(be + cf * 16 + khi * 4);
        if (r0 < Nn) {
            us4 ob = {f2bf((acc0[cf].x - m0) * rs0 * gv.x + ev.x),
                      f2bf((acc0[cf].y - m0) * rs0 * gv.y + ev.y),
                      f2bf((acc0[cf].z - m0) * rs0 * gv.z + ev.z),
                      f2bf((acc0[cf].w - m0) * rs0 * gv.w + ev.w)};
            *(us4*)(outb + (size_t)r0 * DD + cf * 16 + khi * 4) = ob;
        }
        if (r1 < Nn) {
            us4 ob = {f2bf((acc1[cf].x - m1) * rs1 * gv.x + ev.x),
                      f2bf((acc1[cf].y - m1) * rs1 * gv.y + ev.y),
                      f2bf((acc1[cf].z - m1) * rs1 * gv.z + ev.z),
                      f2bf((acc1[cf].w - m1) * rs1 * gv.w + ev.w)};
            *(us4*)(outb + (size_t)r1 * DD + cf * 16 + khi * 4) = ob;
        }
    }
}

// ------------- final GEMM (MFMA): out = relu([h1|h2]@Wl + bl), fp32 out -------------
__global__ __launch_bounds__(256) void gemm_final_mfma(
    const unsigned short* __restrict__ A1, const unsigned short* __restrict__ A2,
    const unsigned short* __restrict__ Wf, const float* __restrict__ bias,
    float* __restrict__ out, int Nn)
{
    const int lane = threadIdx.x & 63;
    const int wid = threadIdx.x >> 6;
    const int rb = (blockIdx.x * 4 + wid) * 32;
    const int rlo = lane & 15, khi = lane >> 4;
    const int r0 = rb + rlo, r1 = rb + 16 + rlo;
    const size_t rr0 = (size_t)min(r0, Nn - 1), rr1 = (size_t)min(r1, Nn - 1);

    bf16x8 aF0[8], aF1[8];
    #pragma unroll
    for (int ks = 0; ks < 4; ++ks) {
        aF0[ks]     = *(const bf16x8*)(A1 + rr0 * DD + ks * 32 + khi * 8);
        aF0[ks + 4] = *(const bf16x8*)(A2 + rr0 * DD + ks * 32 + khi * 8);
        aF1[ks]     = *(const bf16x8*)(A1 + rr1 * DD + ks * 32 + khi * 8);
        aF1[ks + 4] = *(const bf16x8*)(A2 + rr1 * DD + ks * 32 + khi * 8);
    }
    f32x4 acc0[8], acc1[8];
    #pragma unroll
    for (int cf = 0; cf < 8; ++cf) {
        acc0[cf] = (f32x4){0.f, 0.f, 0.f, 0.f};
        acc1[cf] = (f32x4){0.f, 0.f, 0.f, 0.f};
    }
    #pragma unroll
    for (int cf = 0; cf < 8; ++cf) {
        #pragma unroll
        for (int ks = 0; ks < 8; ++ks) {
            bf16x8 wv = *(const bf16x8*)(Wf + ((size_t)(cf * 8 + ks) * 64 + lane) * 8);
            acc0[cf] = MFMA16(wv, aF0[ks], acc0[cf]);
            acc1[cf] = MFMA16(wv, aF1[ks], acc1[cf]);
        }
    }
    #pragma unroll
    for (int cf = 0; cf < 8; ++cf) {
        f32x4 bv = *(const f32x4*)(bias + cf * 16 + khi * 4);
        if (r0 < Nn) {
            f32x4 o;
            o.x = fmaxf(acc0[cf].x + bv.x, 0.f);
            o.y = fmaxf(acc0[cf].y + bv.y, 0.f);
            o.z = fmaxf(acc0[cf].z + bv.z, 0.f);
            o.w = fmaxf(acc0[cf].w + bv.w, 0.f);
            *(f32x4*)(out + (size_t)r0 * DD + cf * 16 + khi * 4) = o;
        }
        if (r1 < Nn) {
            f32x4 o;
            o.x = fmaxf(acc1[cf].x + bv.x, 0.f);
            o.y = fmaxf(acc1[cf].y + bv.y, 0.f);
            o.z = fmaxf(acc1[cf].z + bv.z, 0.f);
            o.w = fmaxf(acc1[cf].w + bv.w, 0.f);
            *(f32x4*)(out + (size_t)r1 * DD + cf * 16 + khi * 4) = o;
        }
    }
}

extern "C" void kernel_launch(void* const* d_in, const int* in_sizes, int n_in,
                              void* d_out, int out_size, void* d_ws, size_t ws_size,
                              hipStream_t stream)
{
    const float* x    = (const float*)d_in[0];
    const int*   ei   = (const int*)d_in[1];
    const float* ea   = (const float*)d_in[2];
    const float* w1a  = (const float*)d_in[4];
    const float* b1a  = (const float*)d_in[5];
    const float* g1a  = (const float*)d_in[6];
    const float* be1a = (const float*)d_in[7];
    const float* w1b  = (const float*)d_in[8];
    const float* b1b  = (const float*)d_in[9];
    const float* w2a  = (const float*)d_in[10];
    const float* b2a  = (const float*)d_in[11];
    const float* g2a  = (const float*)d_in[12];
    const float* be2a = (const float*)d_in[13];
    const float* w2b  = (const float*)d_in[14];
    const float* b2b  = (const float*)d_in[15];
    const float* ng1  = (const float*)d_in[16];
    const float* nb1  = (const float*)d_in[17];
    const float* ng2  = (const float*)d_in[18];
    const float* nb2  = (const float*)d_in[19];
    const float* wl   = (const float*)d_in[20];
    const float* bl   = (const float*)d_in[21];

    const int N = in_sizes[0] / DD;
    const int E = in_sizes[1] / 2;
    const int* src = ei;
    const int* dst = ei + E;

    char* wp = (char*)d_ws;
    auto alloc = [&](size_t bytes) { void* p = wp; wp += (bytes + 255) & ~(size_t)255; return p; };
    unsigned short* aggb = (unsigned short*)alloc((size_t)N * DD * 2);
    unsigned short* mid  = (unsigned short*)alloc((size_t)N * D2 * 2);
    unsigned short* xb   = (unsigned short*)alloc((size_t)N * DD * 2);
    unsigned short* h1b  = (unsigned short*)alloc((size_t)N * DD * 2);
    unsigned short* h2b  = (unsigned short*)alloc((size_t)N * DD * 2);
    unsigned short* eab  = (unsigned short*)alloc((size_t)E * DD * 2);
    unsigned short* WfA1 = (unsigned short*)alloc(32768 * 2);
    unsigned short* WfB1 = (unsigned short*)alloc(32768 * 2);
    unsigned short* WfA2 = (unsigned short*)alloc(32768 * 2);
    unsigned short* WfB2 = (unsigned short*)alloc(32768 * 2);
    unsigned short* WfL  = (unsigned short*)alloc(32768 * 2);
    int* deg    = (int*)alloc((size_t)N * 4);
    int* offs   = (int*)alloc((size_t)(N + 1) * 4);
    int* cursor = (int*)alloc((size_t)N * 4);
    int* bsum   = (int*)alloc(64 * 4);
    int* boff   = (int*)alloc(64 * 4);
    int* eids   = (int*)alloc((size_t)E * 4);

    const int nb = (N + 1023) / 1024;
    const int gE = (E + 255) / 256;
    const int gagg = (N + 3) / 4;
    const int gg = (N + 127) / 128;
    const int gcvt = (N * 16 + 255) / 256;

    (void)hipMemsetAsync(deg, 0, (size_t)N * 4, stream);
    (void)hipMemsetAsync(cursor, 0, (size_t)N * 4, stream);
    cvt_bf16_8<<<gcvt, 256, 0, stream>>>(x, xb, N * 16);
    pack_weights<<<320, 64, 0, stream>>>(w1a, w1b, w2a, w2b, wl, WfA1, WfB1, WfA2, WfB2, WfL);
    hist_kernel<<<gE, 256, 0, stream>>>(dst, deg, E);
    deg_blocksum<<<nb, 256, 0, stream>>>(deg, bsum, N);
    scan_bsums<<<1, 64, 0, stream>>>(bsum, boff, nb, offs, N);
    scan_final<<<nb, 256, 0, stream>>>(deg, boff, offs, N);
    fill_kernel<<<gE, 256, 0, stream>>>(dst, offs, cursor, eids, E);

    // ---- conv1 ----
    aggregate_conv1<<<gagg, 256, 0, stream>>>(xb, ea, eab, src, offs, eids, aggb, N);
    gemm_a_mfma<<<gg, 256, 0, stream>>>(aggb, WfA1, b1a, g1a, be1a, mid, N);
    gemm_b_mfma<<<gg, 256, 0, stream>>>(mid, WfB1, b1b, ng1, nb1, h1b, N);

    // ---- conv2 ----
    aggregate_conv2<<<gagg, 256, 0, stream>>>(h1b, eab, src, offs, eids, aggb, N);
    gemm_a_mfma<<<gg, 256, 0, stream>>>(aggb, WfA2, b2a, g2a, be2a, mid, N);
    gemm_b_mfma<<<gg, 256, 0, stream>>>(mid, WfB2, b2b, ng2, nb2, h2b, N);

    // ---- final ----
    gemm_final_mfma<<<gg, 256, 0, stream>>>(h1b, h2b, WfL, bl, (float*)d_out, N);
}

// Round 6
// 346.380 us; speedup vs baseline: 6.8056x; 1.0415x over previous
//
#include <hip/hip_runtime.h>

#define DD 128
#define D2 256

typedef __attribute__((ext_vector_type(8))) short bf16x8;
typedef __attribute__((ext_vector_type(8))) unsigned short us8;
typedef __attribute__((ext_vector_type(4))) float f32x4;
typedef __attribute__((ext_vector_type(4))) unsigned short us4;

#define MFMA16(a,b,c) __builtin_amdgcn_mfma_f32_16x16x32_bf16(a,b,c,0,0,0)

__device__ __forceinline__ unsigned short f2bf(float f) {
    unsigned int u = __float_as_uint(f);
    u += 0x7FFF + ((u >> 16) & 1);
    return (unsigned short)(u >> 16);
}
__device__ __forceinline__ float bf2f(unsigned short b) {
    return __uint_as_float(((unsigned int)b) << 16);
}

// ---------------- prep: x->bf16 convert  +  degree histogram (fused) ----------------
__global__ __launch_bounds__(256) void prep_kernel(
    const float* __restrict__ x, unsigned short* __restrict__ xb, int n8,
    const int* __restrict__ dst, int* __restrict__ deg, int E, int nbCvt)
{
    if ((int)blockIdx.x < nbCvt) {
        int i = blockIdx.x * 256 + threadIdx.x;
        if (i >= n8) return;
        f32x4 a = *(const f32x4*)(x + (size_t)i * 8);
        f32x4 b = *(const f32x4*)(x + (size_t)i * 8 + 4);
        us8 o = {f2bf(a.x), f2bf(a.y), f2bf(a.z), f2bf(a.w),
                 f2bf(b.x), f2bf(b.y), f2bf(b.z), f2bf(b.w)};
        *(us8*)(xb + (size_t)i * 8) = o;
    } else {
        int e = (blockIdx.x - nbCvt) * 256 + threadIdx.x;
        if (e < E) atomicAdd(&deg[dst[e]], 1);
    }
}

// ---------------- weight pre-pack: fp32 [K][Nc] -> bf16 frag-linear ----------------
__global__ __launch_bounds__(64) void pack_weights(
    const float* __restrict__ w1a, const float* __restrict__ w1b,
    const float* __restrict__ w2a, const float* __restrict__ w2b,
    const float* __restrict__ wl,
    unsigned short* __restrict__ o1a, unsigned short* __restrict__ o1b,
    unsigned short* __restrict__ o2a, unsigned short* __restrict__ o2b,
    unsigned short* __restrict__ ol)
{
    int widx = blockIdx.x >> 6;
    int f = blockIdx.x & 63;
    int lane = threadIdx.x;
    const float* W; unsigned short* O; int nks, Nc;
    switch (widx) {
        case 0: W = w1a; O = o1a; nks = 4; Nc = 256; break;
        case 1: W = w1b; O = o1b; nks = 8; Nc = 128; break;
        case 2: W = w2a; O = o2a; nks = 4; Nc = 256; break;
        case 3: W = w2b; O = o2b; nks = 8; Nc = 128; break;
        default: W = wl; O = ol;  nks = 8; Nc = 128; break;
    }
    int cf = f / nks, ks = f % nks;
    int col = cf * 16 + (lane & 15);
    int k0 = ks * 32 + (lane >> 4) * 8;
    unsigned short t[8];
    #pragma unroll
    for (int j = 0; j < 8; ++j) t[j] = f2bf(W[(size_t)(k0 + j) * Nc + col]);
    us4* dstp = (us4*)(O + ((size_t)f * 64 + lane) * 8);
    dstp[0] = (us4){t[0], t[1], t[2], t[3]};
    dstp[1] = (us4){t[4], t[5], t[6], t[7]};
}

// ---------------- CSR scan ----------------
__global__ __launch_bounds__(256) void deg_blocksum(
    const int* __restrict__ deg, int* __restrict__ bsum, int Nn)
{
    __shared__ int ws[4];
    int b = blockIdx.x, t = threadIdx.x, lane = t & 63, w = t >> 6;
    int i0 = b * 1024 + t * 4;
    int s = 0;
    if (i0 + 3 < Nn) { int4 v = *(const int4*)(deg + i0); s = v.x + v.y + v.z + v.w; }
    else { for (int j = 0; j < 4; ++j) if (i0 + j < Nn) s += deg[i0 + j]; }
    #pragma unroll
    for (int o = 32; o >= 1; o >>= 1) s += __shfl_xor(s, o, 64);
    if (lane == 0) ws[w] = s;
    __syncthreads();
    if (t == 0) bsum[b] = ws[0] + ws[1] + ws[2] + ws[3];
}

__global__ __launch_bounds__(64) void scan_bsums(
    const int* __restrict__ bsum, int* __restrict__ boff, int nb,
    int* __restrict__ offs, int Nn)
{
    int lane = threadIdx.x;
    int v = (lane < nb) ? bsum[lane] : 0;
    int inc = v;
    #pragma unroll
    for (int o = 1; o < 64; o <<= 1) { int n = __shfl_up(inc, o, 64); if (lane >= o) inc += n; }
    if (lane < nb) boff[lane] = inc - v;
    if (lane == 63) offs[Nn] = inc;
}

__global__ __launch_bounds__(256) void scan_final(
    const int* __restrict__ deg, const int* __restrict__ boff,
    int* __restrict__ offs, int* __restrict__ cursor, int Nn)
{
    __shared__ int wsum[4];
    int b = blockIdx.x, t = threadIdx.x, lane = t & 63, w = t >> 6;
    int i0 = b * 1024 + t * 4;
    int a = 0, bb = 0, c = 0, d = 0;
    if (i0 + 3 < Nn) { int4 v = *(const int4*)(deg + i0); a = v.x; bb = v.y; c = v.z; d = v.w; }
    else {
        if (i0     < Nn) a  = deg[i0];
        if (i0 + 1 < Nn) bb = deg[i0 + 1];
        if (i0 + 2 < Nn) c  = deg[i0 + 2];
    }
    int tot = a + bb + c + d, inc = tot;
    #pragma unroll
    for (int o = 1; o < 64; o <<= 1) { int n = __shfl_up(inc, o, 64); if (lane >= o) inc += n; }
    if (lane == 63) wsum[w] = inc;
    __syncthreads();
    int wbase = 0;
    #pragma unroll
    for (int j = 0; j < 4; ++j) if (j < w) wbase += wsum[j];
    int excl = boff[b] + wbase + inc - tot;
    if (i0     < Nn) { offs[i0]     = excl;               cursor[i0]     = excl; }
    if (i0 + 1 < Nn) { offs[i0 + 1] = excl + a;           cursor[i0 + 1] = excl + a; }
    if (i0 + 2 < Nn) { offs[i0 + 2] = excl + a + bb;      cursor[i0 + 2] = excl + a + bb; }
    if (i0 + 3 < Nn) { offs[i0 + 3] = excl + a + bb + c;  cursor[i0 + 3] = excl + a + bb + c; }
}

// fill: slot p = cursor[d]++ ; records edge id AND its src in CSR order
__global__ __launch_bounds__(256) void fill_kernel(
    const int* __restrict__ src, const int* __restrict__ dst,
    int* __restrict__ cursor, int* __restrict__ eids,
    int* __restrict__ srcs, int E)
{
    int e = blockIdx.x * 256 + threadIdx.x;
    if (e < E) {
        int d = dst[e];
        int p = atomicAdd(&cursor[d], 1);
        eids[p] = e;
        srcs[p] = src[e];
    }
}

// --------- aggregate conv1: aggb[n] = bf16( x[n] + sum relu(x[src]+ea) ) ---------
// reads ea (f32, random rows), writes eab in CSR-slot order (sequential).
// 4 edges in flight (16-lane groups), 2-deep unroll.
__global__ __launch_bounds__(256) void aggregate_conv1(
    const unsigned short* __restrict__ xb, const float* __restrict__ ea,
    unsigned short* __restrict__ eab, const int* __restrict__ srcs,
    const int* __restrict__ eids, const int* __restrict__ offs,
    unsigned short* __restrict__ aggb, int Nn)
{
    int node = blockIdx.x * 4 + (threadIdx.x >> 6);
    if (node >= Nn) return;
    int lane = threadIdx.x & 63;
    int g = lane >> 4, c8 = (lane & 15) * 8;
    int beg = offs[node], deg = offs[node + 1] - beg;
    float acc[8] = {};
    if (g == 0) {
        us8 xv = *(const us8*)(xb + (size_t)node * DD + c8);
        #pragma unroll
        for (int j = 0; j < 8; ++j) acc[j] = bf2f(xv[j]);
    }
    for (int idx = g; idx < deg; idx += 8) {
        {
            int pos = beg + idx;
            int e = eids[pos], s = srcs[pos];
            const float* ep = ea + (size_t)e * DD + c8;
            f32x4 e0 = __builtin_nontemporal_load((const f32x4*)ep);
            f32x4 e1 = __builtin_nontemporal_load((const f32x4*)(ep + 4));
            us8 xv = *(const us8*)(xb + (size_t)s * DD + c8);
            us8 eb = {f2bf(e0.x), f2bf(e0.y), f2bf(e0.z), f2bf(e0.w),
                      f2bf(e1.x), f2bf(e1.y), f2bf(e1.z), f2bf(e1.w)};
            __builtin_nontemporal_store(eb, (us8*)(eab + (size_t)pos * DD + c8));
            acc[0] += fmaxf(bf2f(xv[0]) + e0.x, 0.f);
            acc[1] += fmaxf(bf2f(xv[1]) + e0.y, 0.f);
            acc[2] += fmaxf(bf2f(xv[2]) + e0.z, 0.f);
            acc[3] += fmaxf(bf2f(xv[3]) + e0.w, 0.f);
            acc[4] += fmaxf(bf2f(xv[4]) + e1.x, 0.f);
            acc[5] += fmaxf(bf2f(xv[5]) + e1.y, 0.f);
            acc[6] += fmaxf(bf2f(xv[6]) + e1.z, 0.f);
            acc[7] += fmaxf(bf2f(xv[7]) + e1.w, 0.f);
        }
        if (idx + 4 < deg) {
            int pos = beg + idx + 4;
            int e = eids[pos], s = srcs[pos];
            const float* ep = ea + (size_t)e * DD + c8;
            f32x4 e0 = __builtin_nontemporal_load((const f32x4*)ep);
            f32x4 e1 = __builtin_nontemporal_load((const f32x4*)(ep + 4));
            us8 xv = *(const us8*)(xb + (size_t)s * DD + c8);
            us8 eb = {f2bf(e0.x), f2bf(e0.y), f2bf(e0.z), f2bf(e0.w),
                      f2bf(e1.x), f2bf(e1.y), f2bf(e1.z), f2bf(e1.w)};
            __builtin_nontemporal_store(eb, (us8*)(eab + (size_t)pos * DD + c8));
            acc[0] += fmaxf(bf2f(xv[0]) + e0.x, 0.f);
            acc[1] += fmaxf(bf2f(xv[1]) + e0.y, 0.f);
            acc[2] += fmaxf(bf2f(xv[2]) + e0.z, 0.f);
            acc[3] += fmaxf(bf2f(xv[3]) + e0.w, 0.f);
            acc[4] += fmaxf(bf2f(xv[4]) + e1.x, 0.f);
            acc[5] += fmaxf(bf2f(xv[5]) + e1.y, 0.f);
            acc[6] += fmaxf(bf2f(xv[6]) + e1.z, 0.f);
            acc[7] += fmaxf(bf2f(xv[7]) + e1.w, 0.f);
        }
    }
    #pragma unroll
    for (int j = 0; j < 8; ++j) {
        acc[j] += __shfl_xor(acc[j], 16, 64);
        acc[j] += __shfl_xor(acc[j], 32, 64);
    }
    if (g == 0) {
        us8 o = {f2bf(acc[0]), f2bf(acc[1]), f2bf(acc[2]), f2bf(acc[3]),
                 f2bf(acc[4]), f2bf(acc[5]), f2bf(acc[6]), f2bf(acc[7])};
        *(us8*)(aggb + (size_t)node * DD + c8) = o;
    }
}

// --------- aggregate conv2: sequential eab + srcs (CSR order), h gather ---------
__global__ __launch_bounds__(256) void aggregate_conv2(
    const unsigned short* __restrict__ hb, const unsigned short* __restrict__ eab,
    const int* __restrict__ srcs, const int* __restrict__ offs,
    unsigned short* __restrict__ aggb, int Nn)
{
    int node = blockIdx.x * 4 + (threadIdx.x >> 6);
    if (node >= Nn) return;
    int lane = threadIdx.x & 63;
    int g = lane >> 4, c8 = (lane & 15) * 8;
    int beg = offs[node], deg = offs[node + 1] - beg;
    float acc[8] = {};
    if (g == 0) {
        us8 xv = *(const us8*)(hb + (size_t)node * DD + c8);
        #pragma unroll
        for (int j = 0; j < 8; ++j) acc[j] = bf2f(xv[j]);
    }
    for (int idx = g; idx < deg; idx += 8) {
        {
            int pos = beg + idx;
            int s = srcs[pos];
            us8 ev = __builtin_nontemporal_load((const us8*)(eab + (size_t)pos * DD + c8));
            us8 xv = *(const us8*)(hb + (size_t)s * DD + c8);
            #pragma unroll
            for (int j = 0; j < 8; ++j)
                acc[j] += fmaxf(bf2f(xv[j]) + bf2f(ev[j]), 0.f);
        }
        if (idx + 4 < deg) {
            int pos = beg + idx + 4;
            int s = srcs[pos];
            us8 ev = __builtin_nontemporal_load((const us8*)(eab + (size_t)pos * DD + c8));
            us8 xv = *(const us8*)(hb + (size_t)s * DD + c8);
            #pragma unroll
            for (int j = 0; j < 8; ++j)
                acc[j] += fmaxf(bf2f(xv[j]) + bf2f(ev[j]), 0.f);
        }
    }
    #pragma unroll
    for (int j = 0; j < 8; ++j) {
        acc[j] += __shfl_xor(acc[j], 16, 64);
        acc[j] += __shfl_xor(acc[j], 32, 64);
    }
    if (g == 0) {
        us8 o = {f2bf(acc[0]), f2bf(acc[1]), f2bf(acc[2]), f2bf(acc[3]),
                 f2bf(acc[4]), f2bf(acc[5]), f2bf(acc[6]), f2bf(acc[7])};
        *(us8*)(aggb + (size_t)node * DD + c8) = o;
    }
}

// ------------- GEMM A (MFMA): mid = bf16(relu(LN(A@W + b))), A[N,128] -> out[N,256] -------------
__global__ __launch_bounds__(256) void gemm_a_mfma(
    const unsigned short* __restrict__ A, const unsigned short* __restrict__ Wf,
    const float* __restrict__ bias, const float* __restrict__ g,
    const float* __restrict__ be, unsigned short* __restrict__ out, int Nn)
{
    const int lane = threadIdx.x & 63;
    const int wid = threadIdx.x >> 6;
    const int rb = (blockIdx.x * 4 + wid) * 32;
    const int rlo = lane & 15, khi = lane >> 4;
    const int r0 = rb + rlo, r1 = rb + 16 + rlo;
    const size_t rr0 = (size_t)min(r0, Nn - 1), rr1 = (size_t)min(r1, Nn - 1);

    bf16x8 aF0[4], aF1[4];
    #pragma unroll
    for (int ks = 0; ks < 4; ++ks) {
        aF0[ks] = *(const bf16x8*)(A + rr0 * DD + ks * 32 + khi * 8);
        aF1[ks] = *(const bf16x8*)(A + rr1 * DD + ks * 32 + khi * 8);
    }
    f32x4 acc0[16], acc1[16];
    #pragma unroll
    for (int cf = 0; cf < 16; ++cf) {
        acc0[cf] = (f32x4){0.f, 0.f, 0.f, 0.f};
        acc1[cf] = (f32x4){0.f, 0.f, 0.f, 0.f};
    }
    #pragma unroll
    for (int cf = 0; cf < 16; ++cf) {
        #pragma unroll
        for (int ks = 0; ks < 4; ++ks) {
            bf16x8 wv = *(const bf16x8*)(Wf + ((size_t)(cf * 4 + ks) * 64 + lane) * 8);
            acc0[cf] = MFMA16(wv, aF0[ks], acc0[cf]);
            acc1[cf] = MFMA16(wv, aF1[ks], acc1[cf]);
        }
    }
    float s0 = 0.f, q0 = 0.f, s1 = 0.f, q1 = 0.f;
    #pragma unroll
    for (int cf = 0; cf < 16; ++cf) {
        f32x4 bv = *(const f32x4*)(bias + cf * 16 + khi * 4);
        acc0[cf].x += bv.x; acc0[cf].y += bv.y; acc0[cf].z += bv.z; acc0[cf].w += bv.w;
        acc1[cf].x += bv.x; acc1[cf].y += bv.y; acc1[cf].z += bv.z; acc1[cf].w += bv.w;
        s0 += acc0[cf].x + acc0[cf].y + acc0[cf].z + acc0[cf].w;
        q0 += acc0[cf].x * acc0[cf].x + acc0[cf].y * acc0[cf].y + acc0[cf].z * acc0[cf].z + acc0[cf].w * acc0[cf].w;
        s1 += acc1[cf].x + acc1[cf].y + acc1[cf].z + acc1[cf].w;
        q1 += acc1[cf].x * acc1[cf].x + acc1[cf].y * acc1[cf].y + acc1[cf].z * acc1[cf].z + acc1[cf].w * acc1[cf].w;
    }
    s0 += __shfl_xor(s0, 16, 64); s0 += __shfl_xor(s0, 32, 64);
    q0 += __shfl_xor(q0, 16, 64); q0 += __shfl_xor(q0, 32, 64);
    s1 += __shfl_xor(s1, 16, 64); s1 += __shfl_xor(s1, 32, 64);
    q1 += __shfl_xor(q1, 16, 64); q1 += __shfl_xor(q1, 32, 64);
    const float m0 = s0 * (1.f / D2), m1 = s1 * (1.f / D2);
    const float rs0 = rsqrtf(q0 * (1.f / D2) - m0 * m0 + 1e-5f);
    const float rs1 = rsqrtf(q1 * (1.f / D2) - m1 * m1 + 1e-5f);
    #pragma unroll
    for (int cf = 0; cf < 16; ++cf) {
        f32x4 gv = *(const f32x4*)(g + cf * 16 + khi * 4);
        f32x4 ev = *(const f32x4*)(be + cf * 16 + khi * 4);
        if (r0 < Nn) {
            us4 o = {f2bf(fmaxf((acc0[cf].x - m0) * rs0 * gv.x + ev.x, 0.f)),
                     f2bf(fmaxf((acc0[cf].y - m0) * rs0 * gv.y + ev.y, 0.f)),
                     f2bf(fmaxf((acc0[cf].z - m0) * rs0 * gv.z + ev.z, 0.f)),
                     f2bf(fmaxf((acc0[cf].w - m0) * rs0 * gv.w + ev.w, 0.f))};
            *(us4*)(out + (size_t)r0 * D2 + cf * 16 + khi * 4) = o;
        }
        if (r1 < Nn) {
            us4 o = {f2bf(fmaxf((acc1[cf].x - m1) * rs1 * gv.x + ev.x, 0.f)),
                     f2bf(fmaxf((acc1[cf].y - m1) * rs1 * gv.y + ev.y, 0.f)),
                     f2bf(fmaxf((acc1[cf].z - m1) * rs1 * gv.z + ev.z, 0.f)),
                     f2bf(fmaxf((acc1[cf].w - m1) * rs1 * gv.w + ev.w, 0.f))};
            *(us4*)(out + (size_t)r1 * D2 + cf * 16 + khi * 4) = o;
        }
    }
}

// ------------- GEMM B (MFMA): h = LN(relu(X@W + b)); X[N,256] -> bf16 out[N,128] -------------
__global__ __launch_bounds__(256) void gemm_b_mfma(
    const unsigned short* __restrict__ X, const unsigned short* __restrict__ Wf,
    const float* __restrict__ bias, const float* __restrict__ g,
    const float* __restrict__ be, unsigned short* __restrict__ outb, int Nn)
{
    const int lane = threadIdx.x & 63;
    const int wid = threadIdx.x >> 6;
    const int rb = (blockIdx.x * 4 + wid) * 32;
    const int rlo = lane & 15, khi = lane >> 4;
    const int r0 = rb + rlo, r1 = rb + 16 + rlo;
    const size_t rr0 = (size_t)min(r0, Nn - 1), rr1 = (size_t)min(r1, Nn - 1);

    bf16x8 aF0[8], aF1[8];
    #pragma unroll
    for (int ks = 0; ks < 8; ++ks) {
        aF0[ks] = *(const bf16x8*)(X + rr0 * D2 + ks * 32 + khi * 8);
        aF1[ks] = *(const bf16x8*)(X + rr1 * D2 + ks * 32 + khi * 8);
    }
    f32x4 acc0[8], acc1[8];
    #pragma unroll
    for (int cf = 0; cf < 8; ++cf) {
        acc0[cf] = (f32x4){0.f, 0.f, 0.f, 0.f};
        acc1[cf] = (f32x4){0.f, 0.f, 0.f, 0.f};
    }
    #pragma unroll
    for (int cf = 0; cf < 8; ++cf) {
        #pragma unroll
        for (int ks = 0; ks < 8; ++ks) {
            bf16x8 wv = *(const bf16x8*)(Wf + ((size_t)(cf * 8 + ks) * 64 + lane) * 8);
            acc0[cf] = MFMA16(wv, aF0[ks], acc0[cf]);
            acc1[cf] = MFMA16(wv, aF1[ks], acc1[cf]);
        }
    }
    float s0 = 0.f, q0 = 0.f, s1 = 0.f, q1 = 0.f;
    #pragma unroll
    for (int cf = 0; cf < 8; ++cf) {
        f32x4 bv = *(const f32x4*)(bias + cf * 16 + khi * 4);
        acc0[cf].x = fmaxf(acc0[cf].x + bv.x, 0.f); acc0[cf].y = fmaxf(acc0[cf].y + bv.y, 0.f);
        acc0[cf].z = fmaxf(acc0[cf].z + bv.z, 0.f); acc0[cf].w = fmaxf(acc0[cf].w + bv.w, 0.f);
        acc1[cf].x = fmaxf(acc1[cf].x + bv.x, 0.f); acc1[cf].y = fmaxf(acc1[cf].y + bv.y, 0.f);
        acc1[cf].z = fmaxf(acc1[cf].z + bv.z, 0.f); acc1[cf].w = fmaxf(acc1[cf].w + bv.w, 0.f);
        s0 += acc0[cf].x + acc0[cf].y + acc0[cf].z + acc0[cf].w;
        q0 += acc0[cf].x * acc0[cf].x + acc0[cf].y * acc0[cf].y + acc0[cf].z * acc0[cf].z + acc0[cf].w * acc0[cf].w;
        s1 += acc1[cf].x + acc1[cf].y + acc1[cf].z + acc1[cf].w;
        q1 += acc1[cf].x * acc1[cf].x + acc1[cf].y * acc1[cf].y + acc1[cf].z * acc1[cf].z + acc1[cf].w * acc1[cf].w;
    }
    s0 += __shfl_xor(s0, 16, 64); s0 += __shfl_xor(s0, 32, 64);
    q0 += __shfl_xor(q0, 16, 64); q0 += __shfl_xor(q0, 32, 64);
    s1 += __shfl_xor(s1, 16, 64); s1 += __shfl_xor(s1, 32, 64);
    q1 += __shfl_xor(q1, 16, 64); q1 += __shfl_xor(q1, 32, 64);
    const float m0 = s0 * (1.f / DD), m1 = s1 * (1.f / DD);
    const float rs0 = rsqrtf(q0 * (1.f / DD) - m0 * m0 + 1e-5f);
    const float rs1 = rsqrtf(q1 * (1.f / DD) - m1 * m1 + 1e-5f);
    #pragma unroll
    for (int cf = 0; cf < 8; ++cf) {
        f32x4 gv = *(const f32x4*)(g + cf * 16 + khi * 4);
        f32x4 ev = *(const f32x4*)(be + cf * 16 + khi * 4);
        if (r0 < Nn) {
            us4 ob = {f2bf((acc0[cf].x - m0) * rs0 * gv.x + ev.x),
                      f2bf((acc0[cf].y - m0) * rs0 * gv.y + ev.y),
                      f2bf((acc0[cf].z - m0) * rs0 * gv.z + ev.z),
                      f2bf((acc0[cf].w - m0) * rs0 * gv.w + ev.w)};
            *(us4*)(outb + (size_t)r0 * DD + cf * 16 + khi * 4) = ob;
        }
        if (r1 < Nn) {
            us4 ob = {f2bf((acc1[cf].x - m1) * rs1 * gv.x + ev.x),
                      f2bf((acc1[cf].y - m1) * rs1 * gv.y + ev.y),
                      f2bf((acc1[cf].z - m1) * rs1 * gv.z + ev.z),
                      f2bf((acc1[cf].w - m1) * rs1 * gv.w + ev.w)};
            *(us4*)(outb + (size_t)r1 * DD + cf * 16 + khi * 4) = ob;
        }
    }
}

// ------------- final GEMM (MFMA): out = relu([h1|h2]@Wl + bl), fp32 out -------------
__global__ __launch_bounds__(256) void gemm_final_mfma(
    const unsigned short* __restrict__ A1, const unsigned short* __restrict__ A2,
    const unsigned short* __restrict__ Wf, const float* __restrict__ bias,
    float* __restrict__ out, int Nn)
{
    const int lane = threadIdx.x & 63;
    const int wid = threadIdx.x >> 6;
    const int rb = (blockIdx.x * 4 + wid) * 32;
    const int rlo = lane & 15, khi = lane >> 4;
    const int r0 = rb + rlo, r1 = rb + 16 + rlo;
    const size_t rr0 = (size_t)min(r0, Nn - 1), rr1 = (size_t)min(r1, Nn - 1);

    bf16x8 aF0[8], aF1[8];
    #pragma unroll
    for (int ks = 0; ks < 4; ++ks) {
        aF0[ks]     = *(const bf16x8*)(A1 + rr0 * DD + ks * 32 + khi * 8);
        aF0[ks + 4] = *(const bf16x8*)(A2 + rr0 * DD + ks * 32 + khi * 8);
        aF1[ks]     = *(const bf16x8*)(A1 + rr1 * DD + ks * 32 + khi * 8);
        aF1[ks + 4] = *(const bf16x8*)(A2 + rr1 * DD + ks * 32 + khi * 8);
    }
    f32x4 acc0[8], acc1[8];
    #pragma unroll
    for (int cf = 0; cf < 8; ++cf) {
        acc0[cf] = (f32x4){0.f, 0.f, 0.f, 0.f};
        acc1[cf] = (f32x4){0.f, 0.f, 0.f, 0.f};
    }
    #pragma unroll
    for (int cf = 0; cf < 8; ++cf) {
        #pragma unroll
        for (int ks = 0; ks < 8; ++ks) {
            bf16x8 wv = *(const bf16x8*)(Wf + ((size_t)(cf * 8 + ks) * 64 + lane) * 8);
            acc0[cf] = MFMA16(wv, aF0[ks], acc0[cf]);
            acc1[cf] = MFMA16(wv, aF1[ks], acc1[cf]);
        }
    }
    #pragma unroll
    for (int cf = 0; cf < 8; ++cf) {
        f32x4 bv = *(const f32x4*)(bias + cf * 16 + khi * 4);
        if (r0 < Nn) {
            f32x4 o;
            o.x = fmaxf(acc0[cf].x + bv.x, 0.f);
            o.y = fmaxf(acc0[cf].y + bv.y, 0.f);
            o.z = fmaxf(acc0[cf].z + bv.z, 0.f);
            o.w = fmaxf(acc0[cf].w + bv.w, 0.f);
            *(f32x4*)(out + (size_t)r0 * DD + cf * 16 + khi * 4) = o;
        }
        if (r1 < Nn) {
            f32x4 o;
            o.x = fmaxf(acc1[cf].x + bv.x, 0.f);
            o.y = fmaxf(acc1[cf].y + bv.y, 0.f);
            o.z = fmaxf(acc1[cf].z + bv.z, 0.f);
            o.w = fmaxf(acc1[cf].w + bv.w, 0.f);
            *(f32x4*)(out + (size_t)r1 * DD + cf * 16 + khi * 4) = o;
        }
    }
}

extern "C" void kernel_launch(void* const* d_in, const int* in_sizes, int n_in,
                              void* d_out, int out_size, void* d_ws, size_t ws_size,
                              hipStream_t stream)
{
    const float* x    = (const float*)d_in[0];
    const int*   ei   = (const int*)d_in[1];
    const float* ea   = (const float*)d_in[2];
    const float* w1a  = (const float*)d_in[4];
    const float* b1a  = (const float*)d_in[5];
    const float* g1a  = (const float*)d_in[6];
    const float* be1a = (const float*)d_in[7];
    const float* w1b  = (const float*)d_in[8];
    const float* b1b  = (const float*)d_in[9];
    const float* w2a  = (const float*)d_in[10];
    const float* b2a  = (const float*)d_in[11];
    const float* g2a  = (const float*)d_in[12];
    const float* be2a = (const float*)d_in[13];
    const float* w2b  = (const float*)d_in[14];
    const float* b2b  = (const float*)d_in[15];
    const float* ng1  = (const float*)d_in[16];
    const float* nb1  = (const float*)d_in[17];
    const float* ng2  = (const float*)d_in[18];
    const float* nb2  = (const float*)d_in[19];
    const float* wl   = (const float*)d_in[20];
    const float* bl   = (const float*)d_in[21];

    const int N = in_sizes[0] / DD;
    const int E = in_sizes[1] / 2;
    const int* src = ei;
    const int* dst = ei + E;

    char* wp = (char*)d_ws;
    auto alloc = [&](size_t bytes) { void* p = wp; wp += (bytes + 255) & ~(size_t)255; return p; };
    unsigned short* aggb = (unsigned short*)alloc((size_t)N * DD * 2);
    unsigned short* mid  = (unsigned short*)alloc((size_t)N * D2 * 2);
    unsigned short* xb   = (unsigned short*)alloc((size_t)N * DD * 2);
    unsigned short* h1b  = (unsigned short*)alloc((size_t)N * DD * 2);
    unsigned short* h2b  = (unsigned short*)alloc((size_t)N * DD * 2);
    unsigned short* eab  = (unsigned short*)alloc((size_t)E * DD * 2);
    unsigned short* WfA1 = (unsigned short*)alloc(32768 * 2);
    unsigned short* WfB1 = (unsigned short*)alloc(32768 * 2);
    unsigned short* WfA2 = (unsigned short*)alloc(32768 * 2);
    unsigned short* WfB2 = (unsigned short*)alloc(32768 * 2);
    unsigned short* WfL  = (unsigned short*)alloc(32768 * 2);
    int* deg    = (int*)alloc((size_t)N * 4);
    int* offs   = (int*)alloc((size_t)(N + 1) * 4);
    int* cursor = (int*)alloc((size_t)N * 4);
    int* bsum   = (int*)alloc(64 * 4);
    int* boff   = (int*)alloc(64 * 4);
    int* eids   = (int*)alloc((size_t)E * 4);
    int* srcs   = (int*)alloc((size_t)E * 4);

    const int nb = (N + 1023) / 1024;
    const int gE = (E + 255) / 256;
    const int gagg = (N + 3) / 4;
    const int gg = (N + 127) / 128;
    const int n8 = N * 16;
    const int gcvt = (n8 + 255) / 256;

    (void)hipMemsetAsync(deg, 0, (size_t)N * 4, stream);
    prep_kernel<<<gcvt + gE, 256, 0, stream>>>(x, xb, n8, dst, deg, E, gcvt);
    pack_weights<<<320, 64, 0, stream>>>(w1a, w1b, w2a, w2b, wl, WfA1, WfB1, WfA2, WfB2, WfL);
    deg_blocksum<<<nb, 256, 0, stream>>>(deg, bsum, N);
    scan_bsums<<<1, 64, 0, stream>>>(bsum, boff, nb, offs, N);
    scan_final<<<nb, 256, 0, stream>>>(deg, boff, offs, cursor, N);
    fill_kernel<<<gE, 256, 0, stream>>>(src, dst, cursor, eids, srcs, E);

    // ---- conv1 ----
    aggregate_conv1<<<gagg, 256, 0, stream>>>(xb, ea, eab, srcs, eids, offs, aggb, N);
    gemm_a_mfma<<<gg, 256, 0, stream>>>(aggb, WfA1, b1a, g1a, be1a, mid, N);
    gemm_b_mfma<<<gg, 256, 0, stream>>>(mid, WfB1, b1b, ng1, nb1, h1b, N);

    // ---- conv2 ----
    aggregate_conv2<<<gagg, 256, 0, stream>>>(h1b, eab, srcs, offs, aggb, N);
    gemm_a_mfma<<<gg, 256, 0, stream>>>(aggb, WfA2, b2a, g2a, be2a, mid, N);
    gemm_b_mfma<<<gg, 256, 0, stream>>>(mid, WfB2, b2b, ng2, nb2, h2b, N);

    // ---- final ----
    gemm_final_mfma<<<gg, 256, 0, stream>>>(h1b, h2b, WfL, bl, (float*)d_out, N);
}